// Round 6
// baseline (1482.405 us; speedup 1.0000x reference)
//
#include <hip/hip_runtime.h>
#include <hip/hip_bf16.h>
#include <cstdint>
#include <cstddef>

// ---------------- problem constants ----------------
#define NH    64
#define NB    384
#define EDIM  1024
#define PAIRS (NH*NB)   // 24576
#define SPA   36

using in_t  = float;
using out_t = float;
using sb_t  = __hip_bfloat16;

typedef short bf16x8 __attribute__((ext_vector_type(8)));
typedef float f32x4  __attribute__((ext_vector_type(4)));

static __device__ __forceinline__ float cvt(float x){ return x; }
static __device__ __forceinline__ float cvt(__hip_bfloat16 x){ return __bfloat162float(x); }
static __device__ __forceinline__ void stv(float* p, float v){ *p = v; }
static __device__ __forceinline__ void stv(__hip_bfloat16* p, float v){ *p = __float2bfloat16(v); }

static __device__ __forceinline__ float b2f(unsigned short u){
  union { unsigned int i; float f; } x; x.i = ((unsigned int)u)<<16; return x.f;
}

typedef const __attribute__((address_space(1))) void* as1_t;
typedef __attribute__((address_space(3))) void* as3_t;
static __device__ __forceinline__ void gl_lds16(const void* g, void* l){
  __builtin_amdgcn_global_load_lds((as1_t)g, (as3_t)l, 16, 0, 0);
}

// ---------------- bias/constant pool layout (floats) ----------------
#define POOL_BB1   0
#define POOL_BB2   1024
#define POOL_BS1   2048
#define POOL_BS2   2176
#define POOL_BS3   2432
#define POOL_AB1   3456
#define POOL_GB1   4480
#define POOL_SB1   5504
#define POOL_OB1   6528
#define POOL_B2ALL 7552          // 4096: [AB2|OB2|SB2|GB2]
#define POOL_AB3S  11648
#define POOL_GB3S  12672
#define POOL_SB3S  13696
#define POOL_OB3S  14720
#define POOL_GFEAT 15744
#define POOL_TOTAL 16000

// ============================================================================
// MFMA bf16 GEMM, 128x128 tile, BK=64 (two 32-wide sub-tiles), 4 waves.
// (kept for small/odd shapes; EPI2 = split-K partial writer)
// ============================================================================
template<int EPI, int RELU, typename TC>
__global__ __launch_bounds__(256)
void gemm_mfma(int M, int N, int KS, int lda, int ldb,
               const sb_t* __restrict__ A,
               const sb_t* __restrict__ Bt,
               const float* __restrict__ bias,
               TC* __restrict__ C, int ldc, int coff, long long strideCz,
               const float* __restrict__ Wadj,
               const float* __restrict__ ab3s,
               float* __restrict__ adjOut)
{
  __shared__ alignas(16) short lA[2][128*32];
  __shared__ alignas(16) short lB[2][128*32];
  const int tid = threadIdx.x;
  const int w = tid >> 6, l = tid & 63;
  const int m0 = blockIdx.x * 128, n0 = blockIdx.y * 128;
  const int wr = w >> 1, wc = w & 1;
  const int Koff = blockIdx.z * KS;

  const int srow = w*32 + (l>>2);
  const int scol = (l&3)*8;
  const sb_t* gA = A  + (size_t)(m0 + srow)*(size_t)lda + Koff + scol;
  const sb_t* gB = Bt + (size_t)(n0 + srow)*(size_t)ldb + Koff + scol;
  short* lA0 = &lA[0][(w*32)*32];
  short* lA1 = &lA[1][(w*32)*32];
  short* lB0 = &lB[0][(w*32)*32];
  short* lB1 = &lB[1][(w*32)*32];

  f32x4 acc[4][4];
  const f32x4 zz = {0.f,0.f,0.f,0.f};
  #pragma unroll
  for (int i=0;i<4;++i)
    #pragma unroll
    for (int j=0;j<4;++j) acc[i][j] = zz;

  const int fr  = l & 15;
  const int fko = (l >> 4) * 8;

  for (int k0 = 0; k0 < KS; k0 += 64) {
    gl_lds16(gA + k0,               lA0);
    gl_lds16(gA + k0 + 16*lda,      lA0 + 16*32);
    gl_lds16(gA + k0 + 32,          lA1);
    gl_lds16(gA + k0 + 32 + 16*lda, lA1 + 16*32);
    gl_lds16(gB + k0,               lB0);
    gl_lds16(gB + k0 + 16*ldb,      lB0 + 16*32);
    gl_lds16(gB + k0 + 32,          lB1);
    gl_lds16(gB + k0 + 32 + 16*ldb, lB1 + 16*32);
    __syncthreads();
    #pragma unroll
    for (int kh=0; kh<2; ++kh) {
      bf16x8 af[4], bfv[4];
      #pragma unroll
      for (int i=0;i<4;++i)
        af[i]  = *(const bf16x8*)&lA[kh][(wr*64 + i*16 + fr)*32 + fko];
      #pragma unroll
      for (int j=0;j<4;++j)
        bfv[j] = *(const bf16x8*)&lB[kh][(wc*64 + j*16 + fr)*32 + fko];
      #pragma unroll
      for (int i=0;i<4;++i)
        #pragma unroll
        for (int j=0;j<4;++j)
          acc[i][j] = __builtin_amdgcn_mfma_f32_16x16x32_bf16(af[i], bfv[j], acc[i][j], 0, 0, 0);
    }
    __syncthreads();
  }

  const int cn = l & 15;
  const int cr = (l >> 4) * 4;

  if (EPI == 1) {
    float part[4][4];
    #pragma unroll
    for (int i=0;i<4;++i)
      #pragma unroll
      for (int r=0;r<4;++r) part[i][r] = 0.f;
    #pragma unroll
    for (int j=0;j<4;++j) {
      const int col = n0 + wc*64 + j*16 + cn;
      const float wv = Wadj[col];
      const float bv = ab3s[col];
      #pragma unroll
      for (int i=0;i<4;++i)
        #pragma unroll
        for (int r=0;r<4;++r)
          part[i][r] += fmaxf(acc[i][j][r] + bv, 0.f) * wv;
    }
    #pragma unroll
    for (int m=1;m<16;m<<=1)
      #pragma unroll
      for (int i=0;i<4;++i)
        #pragma unroll
        for (int r=0;r<4;++r)
          part[i][r] += __shfl_xor(part[i][r], m, 64);
    if (cn == 0) {
      #pragma unroll
      for (int i=0;i<4;++i)
        #pragma unroll
        for (int r=0;r<4;++r)
          atomicAdd(&adjOut[m0 + wr*64 + i*16 + cr + r], part[i][r]);
    }
    return;
  }

  #pragma unroll
  for (int j=0;j<4;++j) {
    const int col = n0 + wc*64 + j*16 + cn;
    const float bv = (EPI==0 && bias) ? bias[col] : 0.f;
    #pragma unroll
    for (int i=0;i<4;++i) {
      #pragma unroll
      for (int r=0;r<4;++r) {
        const int row = m0 + wr*64 + i*16 + cr + r;
        float v = acc[i][j][r] + bv;
        if (RELU) v = fmaxf(v, 0.f);
        if (EPI == 2)
          stv(&C[(size_t)blockIdx.z*strideCz + (size_t)row*ldc + col], v);
        else
          stv(&C[(size_t)row*ldc + coff + col], v);
      }
    }
  }
}

// ============================================================================
// 256x256 8-phase MFMA GEMM, 16x16x32 MFMA, PIPELINED ds_reads (r6):
// A-operand reads issued one phase ahead; pre-MFMA wait is counted
// lgkmcnt(4) (LDS returns in-order per wave -> <=4 outstanding means the
// previous phase's operands landed, typically during the barrier wait).
// Hazards audited: same-tile stage overwrites (S0/S1: B after full B read;
// S2: A rows {0-63,128-191} = ph0/ph1 rows, consumed by MFMA(0)/(1) earlier).
// T1 XCD-swizzle, T2 LDS XOR-swizzle (chunk ^= row&7), T3/T4 counted vmcnt(6),
// T5 setprio. C = A[M,K] @ Bt[N,K]^T ; M%256==0, N%256==0, K%64==0, K>=128.
// Epilogue: C-tile staged through 128 KiB LDS with chunk-XOR swizzle.
// ============================================================================
template<int EPI, int RELU, typename TC>
__global__ __launch_bounds__(512, 2)
void gemm256(int M, int N, int K, int lda, int ldb,
             const sb_t* __restrict__ A,
             const sb_t* __restrict__ Bt,
             const float* __restrict__ bias,
             TC* __restrict__ C, int ldc, int coff,
             const float* __restrict__ Wadj,
             const float* __restrict__ ab3s,
             float* __restrict__ adjOut)
{
  __shared__ alignas(16) short sh[2][2][256*64];   // [buf][0=A,1=B], 128 KiB

  const int tid = threadIdx.x;
  const int w = tid >> 6, l = tid & 63;
  const int wr = w >> 2, wc = w & 3;

  // T1: XCD-chunked bijective swizzle, y-fastest within chunk.
  const unsigned gx = gridDim.x, gy = gridDim.y;
  const unsigned nwg = gx * gy;
  const unsigned hwid = blockIdx.x + gx * blockIdx.y;
  const unsigned q = nwg >> 3, rr = nwg & 7;
  const unsigned xcd = hwid & 7, jj = hwid >> 3;
  const unsigned wg = (xcd < rr ? xcd*(q+1) : rr*(q+1) + (xcd-rr)*q) + jj;
  const int by = (int)(wg % gy), bx = (int)(wg / gy);
  const int m0 = bx * 256, n0 = by * 256;

  const int NT = K >> 6;

  // staging: lane l covers row (l>>3), dest chunk (l&7); source pre-swizzled.
  const int lr = l >> 3;
  const int lch = ((l & 7) ^ lr) * 8;

  auto stage = [&](int p, int s, int t){
    short* lbA = &sh[p][0][0];
    short* lbB = &sh[p][1][0];
    const int k0 = t * 64;
    #pragma unroll
    for (int c=0;c<2;++c){
      const int g = (w<<1) + c;          // 0..15, wave-uniform
      int row0; const sb_t* mat; int ld; int rb; short* dst;
      if (s==0){ row0 = g*8;                              mat=Bt; ld=ldb; rb=n0; dst=lbB; }
      else if (s==1){ row0 = 128 + g*8;                   mat=Bt; ld=ldb; rb=n0; dst=lbB; }
      else if (s==2){ row0 = (g<8)? g*8    : 128+(g-8)*8; mat=A;  ld=lda; rb=m0; dst=lbA; }
      else          { row0 = (g<8)? 64+g*8 : 192+(g-8)*8; mat=A;  ld=lda; rb=m0; dst=lbA; }
      gl_lds16(mat + (size_t)(rb + row0 + lr)*(size_t)ld + k0 + lch, dst + row0*64);
    }
  };

  // fragment-read per-lane constants (16x16x32 layout)
  const int fr = l & 15;
  const int fg = l >> 4;
  const int sx = fr & 7;
  const int x0 = ((0 + fg) ^ sx) * 8;    // kk=0 swizzled chunk (shorts)
  const int x1 = ((4 + fg) ^ sx) * 8;    // kk=1
  const int oA = (wr*128 + fr) * 64;
  const int oB = (wc*64  + fr) * 64;

  f32x4 acc[8][4];
  const f32x4 zz = {0.f,0.f,0.f,0.f};
  #pragma unroll
  for (int i=0;i<8;++i)
    #pragma unroll
    for (int j=0;j<4;++j) acc[i][j] = zz;

#define G256_BAR()   __builtin_amdgcn_s_barrier()
#define G256_LGKM(n) asm volatile("s_waitcnt lgkmcnt(" #n ")" ::: "memory")
#define G256_VM(n)   asm volatile("s_waitcnt vmcnt(" #n ")" ::: "memory")
#define G256_LOADA(AF, ph)                                               \
  AF[0][0] = *(const bf16x8*)(sa + oA + (2*(ph)+0)*1024 + x0);           \
  AF[0][1] = *(const bf16x8*)(sa + oA + (2*(ph)+0)*1024 + x1);           \
  AF[1][0] = *(const bf16x8*)(sa + oA + (2*(ph)+1)*1024 + x0);           \
  AF[1][1] = *(const bf16x8*)(sa + oA + (2*(ph)+1)*1024 + x1)
#define G256_MFMA(ph, AF)                                                \
  do { __builtin_amdgcn_s_setprio(1);                                    \
    _Pragma("unroll") for (int kk=0; kk<2; ++kk)                         \
    _Pragma("unroll") for (int ii=0; ii<2; ++ii)                         \
    _Pragma("unroll") for (int j=0; j<4; ++j)                            \
      acc[2*(ph)+ii][j] = __builtin_amdgcn_mfma_f32_16x16x32_bf16(       \
          AF[ii][kk], bf[j][kk], acc[2*(ph)+ii][j], 0, 0, 0);            \
    __builtin_amdgcn_s_setprio(0); } while(0)

  // ---- prologue: tile0 S0..S3, vm(4), tile1 S0..S2, vm(6) ----
  stage(0,0,0); stage(0,1,0); stage(0,2,0); stage(0,3,0);
  G256_VM(4);
  if (NT > 1) {
    stage(1,0,1); stage(1,1,1); stage(1,2,1);
    G256_VM(6);
  } else {
    G256_VM(0);
  }
  G256_BAR();

  for (int t=0; t<NT; ++t) {
    const int cur = t & 1, pn = cur ^ 1;
    short* sa  = &sh[cur][0][0];
    short* sb2 = &sh[cur][1][0];
    bf16x8 bf[4][2], afp[2][2], afq[2][2];

    // ---- P1: read B(8) + A-ph0(4) + A-ph1(4) ----
    #pragma unroll
    for (int j=0;j<4;++j){
      bf[j][0] = *(const bf16x8*)(sb2 + oB + j*1024 + x0);
      bf[j][1] = *(const bf16x8*)(sb2 + oB + j*1024 + x1);
    }
    G256_LOADA(afp, 0);
    G256_LOADA(afq, 1);
    if (t+1 < NT) stage(pn, 3, t+1);
    G256_BAR(); G256_LGKM(4);      // B + A-ph0 landed; A-ph1 may fly
    G256_MFMA(0, afp);
    G256_BAR();

    // ---- P2: prefetch A-ph2, compute with A-ph1 ----
    G256_LOADA(afp, 2);
    if (t+2 < NT) stage(cur, 0, t+2);
    G256_BAR(); G256_LGKM(4);      // A-ph1 landed; A-ph2 may fly
    G256_MFMA(1, afq);
    G256_BAR();

    // ---- P3: prefetch A-ph3, compute with A-ph2 ----
    G256_LOADA(afq, 3);
    if (t+2 < NT) stage(cur, 1, t+2);
    G256_BAR(); G256_LGKM(4);      // A-ph2 landed; A-ph3 may fly
    G256_MFMA(2, afp);
    G256_BAR();

    // ---- P4: compute with A-ph3 ----
    if (t+2 < NT) stage(cur, 2, t+2);
    G256_BAR(); G256_LGKM(0);
    G256_MFMA(3, afq);
    if (t+1 < NT) {
      if (t+2 < NT) { G256_VM(6); } else { G256_VM(0); }
      G256_BAR();
    }
  }

#undef G256_LOADA
#undef G256_MFMA

  // ---- epilogue ----
  const int cn = l & 15;
  const int cr = (l >> 4) * 4;

  if (EPI == 1) {
    float part[8][4];
    #pragma unroll
    for (int i=0;i<8;++i)
      #pragma unroll
      for (int r=0;r<4;++r) part[i][r] = 0.f;
    #pragma unroll
    for (int j=0;j<4;++j) {
      const int col = n0 + wc*64 + j*16 + cn;
      const float wv = Wadj[col];
      const float bv = ab3s[col];
      #pragma unroll
      for (int i=0;i<8;++i)
        #pragma unroll
        for (int r=0;r<4;++r)
          part[i][r] += fmaxf(acc[i][j][r] + bv, 0.f) * wv;
    }
    #pragma unroll
    for (int m=1;m<16;m<<=1)
      #pragma unroll
      for (int i=0;i<8;++i)
        #pragma unroll
        for (int r=0;r<4;++r)
          part[i][r] += __shfl_xor(part[i][r], m, 64);
    if (cn == 0) {
      #pragma unroll
      for (int i=0;i<8;++i)
        #pragma unroll
        for (int r=0;r<4;++r)
          atomicAdd(&adjOut[m0 + wr*128 + i*16 + cr + r], part[i][r]);
    }
    return;
  }

  // EPI0: LDS-staged coalesced C store (chunk-XOR swizzled)
  if constexpr (sizeof(TC) == 2) {
    sb_t* ebs = (sb_t*)&sh[0][0][0];     // 256x256 bf16 = 128 KiB
    G256_LGKM(0);
    G256_BAR();
    #pragma unroll
    for (int i=0;i<8;++i){
      #pragma unroll
      for (int j=0;j<4;++j){
        const int lcol = wc*64 + j*16 + cn;
        const float bv = bias ? bias[n0 + lcol] : 0.f;
        const int cb = lcol >> 3, ce = lcol & 7;
        #pragma unroll
        for (int r=0;r<4;++r){
          const int lrow = wr*128 + i*16 + cr + r;
          float v = acc[i][j][r] + bv;
          if (RELU) v = fmaxf(v, 0.f);
          stv(&ebs[lrow*256 + ((cb ^ (lrow & 7)) << 3) + ce], v);
        }
      }
    }
    G256_LGKM(0);
    G256_BAR();
    #pragma unroll
    for (int p=0;p<16;++p){
      const int R = p*16 + (tid>>5);
      const int c = tid & 31;
      bf16x8 v = *(const bf16x8*)((const short*)ebs + R*256 + ((c ^ (R & 7)) << 3));
      *(bf16x8*)((short*)C + (size_t)(m0+R)*ldc + coff + n0 + c*8) = v;
    }
  } else {
    // f32: two 128-row passes
    float* ebf = (float*)&sh[0][0][0];   // 128x256 f32 = 128 KiB
    #pragma unroll
    for (int h=0; h<2; ++h){
      G256_LGKM(0);
      G256_BAR();
      if (wr == h){
        #pragma unroll
        for (int i=0;i<8;++i){
          #pragma unroll
          for (int j=0;j<4;++j){
            const int lcol = wc*64 + j*16 + cn;
            const float bv = bias ? bias[n0 + lcol] : 0.f;
            const int cb = lcol >> 2, ce = lcol & 3;
            #pragma unroll
            for (int r=0;r<4;++r){
              const int lrow = i*16 + cr + r;
              float v = acc[i][j][r] + bv;
              if (RELU) v = fmaxf(v, 0.f);
              ebf[lrow*256 + ((cb ^ (lrow & 7)) << 2) + ce] = v;
            }
          }
        }
      }
      G256_LGKM(0);
      G256_BAR();
      #pragma unroll
      for (int p=0;p<16;++p){
        const int R = p*8 + (tid>>6);
        const int c = tid & 63;
        f32x4 v = *(const f32x4*)&ebf[R*256 + ((c ^ (R & 7)) << 2)];
        *(f32x4*)((float*)C + (size_t)(m0 + h*128 + R)*ldc + coff + n0 + c*4) = v;
      }
    }
  }
#undef G256_BAR
#undef G256_LGKM
#undef G256_VM
}

// ============================================================================
// fp32 VALU GEMM (tiny/odd shapes: spatial 36->128, gfeat@G1)
// ============================================================================
template<typename TC>
__global__ __launch_bounds__(256)
void gemm_valu(int M, int N, int K,
               const in_t* __restrict__ S, int ldsS,
               const in_t* __restrict__ B, int ldb, long long strideB,
               const float* __restrict__ bias,
               TC* __restrict__ C, int ldc, int reluOut)
{
  __shared__ float As[16][65];
  __shared__ float Bs[16][68];
  const int z  = blockIdx.z;
  const in_t* Bz = B + (long long)z * strideB;
  const int m0 = blockIdx.x * 64;
  const int n0 = blockIdx.y * 64;
  const int tid = threadIdx.x;
  const int tx = tid & 15;
  const int ty = tid >> 4;

  float acc[4][4];
  #pragma unroll
  for (int i=0;i<4;++i)
    #pragma unroll
    for (int j=0;j<4;++j) acc[i][j]=0.f;

  const int kTiles = (K + 15) >> 4;
  for (int kt=0; kt<kTiles; ++kt) {
    const int k0 = kt << 4;
    #pragma unroll
    for (int q=0;q<4;++q) {
      const int p = m0 + ty + 16*q;
      const int c = k0 + tx;
      As[tx][ty+16*q] = (p < M && c < K) ? S[(size_t)p*ldsS + c] : 0.f;
    }
    {
      const int n = tid & 63;
      #pragma unroll
      for (int q=0;q<4;++q) {
        const int kk = (tid >> 6) + 4*q;
        const int gk = k0 + kk;
        const int gn = n0 + n;
        Bs[kk][n] = (gk < K && gn < N) ? Bz[(size_t)gk*ldb + gn] : 0.f;
      }
    }
    __syncthreads();
    #pragma unroll
    for (int kk=0; kk<16; ++kk) {
      float a[4], b[4];
      #pragma unroll
      for (int i=0;i<4;++i) a[i] = As[kk][ty + 16*i];
      #pragma unroll
      for (int j=0;j<4;++j) b[j] = Bs[kk][tx + 16*j];
      #pragma unroll
      for (int i=0;i<4;++i)
        #pragma unroll
        for (int j=0;j<4;++j) acc[i][j] += a[i]*b[j];
    }
    __syncthreads();
  }
  #pragma unroll
  for (int i=0;i<4;++i) {
    const int r = m0 + ty + 16*i;
    if (r >= M) continue;
    #pragma unroll
    for (int j=0;j<4;++j) {
      const int nn = n0 + tx + 16*j;
      if (nn >= N) continue;
      const int ccol = z*N + nn;
      float v = acc[i][j];
      if (bias) v += bias[ccol];
      if (reluOut) v = fmaxf(v, 0.f);
      stv(&C[(size_t)r*ldc + ccol], v);
    }
  }
}

// ============================================================================
// prep kernels
// ============================================================================
struct Prep17 { const in_t* p[17]; };

__global__ __launch_bounds__(256)
void prep_kernel(Prep17 a, float* __restrict__ pool)
{
  const int len[17] = {1024,1024,128,256,1024,1024,1024,1024,1024,1024,1024,1024,1024,
                       1024,1024,1024,1024};
  const int off[17] = {POOL_BB1,POOL_BB2,POOL_BS1,POOL_BS2,POOL_BS3,POOL_AB1,
                       POOL_B2ALL+0,      // AB2
                       POOL_GB1,
                       POOL_B2ALL+3072,   // GB2
                       POOL_SB1,
                       POOL_B2ALL+2048,   // SB2
                       POOL_OB1,
                       POOL_B2ALL+1024,   // OB2
                       POOL_AB3S,POOL_GB3S,POOL_SB3S,POOL_OB3S};
  const int j = blockIdx.x;
  const in_t* src = a.p[j];
  const int L = len[j], o = off[j];
  for (int i = threadIdx.x; i < L; i += blockDim.x) {
    if (j < 13) {
      pool[o+i] = src[i];
    } else {
      float s = 0.f;
      for (int k=0;k<16;++k) s += src[k*1024 + i];
      pool[o+i] = s;
    }
  }
}

__global__ __launch_bounds__(64)
void gfeat_kernel(const in_t* __restrict__ f3, float* __restrict__ g)
{
  const int c = blockIdx.x;
  const int t = threadIdx.x;
  float s = (t < 49) ? f3[c*49 + t] : 0.f;
  #pragma unroll
  for (int o=32;o>0;o>>=1) s += __shfl_down(s, o, 64);
  if (t == 0) g[c] = s * (1.0f/49.0f);
}

// f32 (R x C) -> bf16 (C x R)
__global__ __launch_bounds__(256)
void tcvt_kernel(const float* __restrict__ in, sb_t* __restrict__ outT, int R, int C)
{
  __shared__ float t[64][65];
  const int r0 = blockIdx.x*64, c0 = blockIdx.y*64;
  const int x = threadIdx.x & 63, y = threadIdx.x >> 6;
  #pragma unroll 4
  for (int q=0;q<16;++q){ const int rl = q*4 + y; t[rl][x] = in[(size_t)(r0+rl)*C + c0 + x]; }
  __syncthreads();
  #pragma unroll 4
  for (int q=0;q<16;++q){ const int cl = q*4 + y; stv(&outT[(size_t)(c0+cl)*R + r0 + x], t[x][cl]); }
}

// W (16, Cdim, 64) f32 -> PT[k*64+u][c] bf16
__global__ __launch_bounds__(256)
void pack_kt_kernel(const float* __restrict__ W, sb_t* __restrict__ PT, int Cdim)
{
  __shared__ float t[64][65];
  const int c0 = blockIdx.x*64; const int k = blockIdx.y;
  const int x = threadIdx.x & 63, y = threadIdx.x >> 6;
  #pragma unroll 4
  for (int q=0;q<16;++q){ const int cl = q*4 + y; t[cl][x] = W[((size_t)k*Cdim + c0 + cl)*64 + x]; }
  __syncthreads();
  #pragma unroll 4
  for (int q=0;q<16;++q){ const int u = q*4 + y; stv(&PT[((size_t)k*64 + u)*Cdim + c0 + x], t[x][u]); }
}

__global__ void cvt_kernel(const float* __restrict__ in, sb_t* __restrict__ o, int n){
  const int i = blockIdx.x*256 + threadIdx.x;
  if (i < n) stv(&o[i], in[i]);
}

// generic split-K combine: out[i] = (relu?)( sum_z part[z*stride+i] + bias[i&(N-1)] )
template<typename TO>
__global__ __launch_bounds__(256)
void combineN_kernel(const float* __restrict__ part, long long stride, int nz,
                     const float* __restrict__ bias, int N, int relu,
                     TO* __restrict__ out)
{
  const int i = blockIdx.x*256 + threadIdx.x;
  float v = bias ? bias[i & (N-1)] : 0.f;
  for (int z=0; z<nz; ++z) v += part[(long long)z*stride + i];
  if (relu) v = fmaxf(v, 0.f);
  stv(&out[i], v);
}

// enc fp32 -> bf16 mirror + h fp32/bf16 copies
__global__ __launch_bounds__(256)
void encpost_kernel(const float* __restrict__ oB, sb_t* __restrict__ oBb,
                    float* __restrict__ hB, sb_t* __restrict__ hBb)
{
  const int p = blockIdx.x; const int c = blockIdx.y*256 + threadIdx.x;
  const float v = oB[(size_t)p*1024 + c];
  stv(&oBb[(size_t)p*1024+c], v);
  if (p < NH){ hB[(size_t)p*1024+c] = v; stv(&hBb[(size_t)p*1024+c], v); }
}

// m[p,c] = bf16( relu( (U[p/NB,c] + V[p%NB,c]) * S4[p, colOff+c] ) )
__global__ __launch_bounds__(256)
void mmake_kernel(const float* __restrict__ U, int hasU, int ldu,
                  const float* __restrict__ V, int hasV,
                  const sb_t* __restrict__ S, int ldS, int colOff,
                  sb_t* __restrict__ Mo)
{
  const int p = blockIdx.x;
  const int c = threadIdx.x * 4;
  const ushort4 sv = *(const ushort4*)((const unsigned short*)S + (size_t)p*ldS + colOff + c);
  float a0=0.f,a1=0.f,a2=0.f,a3=0.f;
  if (hasU){ const float* Up = U + (size_t)(p/NB)*ldu + c; a0=Up[0];a1=Up[1];a2=Up[2];a3=Up[3]; }
  if (hasV){ const float* Vp = V + (size_t)(p%NB)*1024 + c; a0+=Vp[0];a1+=Vp[1];a2+=Vp[2];a3+=Vp[3]; }
  __hip_bfloat16* mo = (__hip_bfloat16*)Mo + (size_t)p*1024 + c;
  mo[0] = __float2bfloat16(fmaxf(a0*b2f(sv.x),0.f));
  mo[1] = __float2bfloat16(fmaxf(a1*b2f(sv.y),0.f));
  mo[2] = __float2bfloat16(fmaxf(a2*b2f(sv.z),0.f));
  mo[3] = __float2bfloat16(fmaxf(a3*b2f(sv.w),0.f));
}

// softmax over n of adj[hh,:] -> wh[hh,n]
__global__ __launch_bounds__(512)
void smax_h_kernel(const float* __restrict__ adj, float* __restrict__ wh)
{
  __shared__ float red[512];
  const int hh = blockIdx.x, t = threadIdx.x;
  float av = (t < NB) ? adj[hh*NB + t] : -1e30f;
  red[t]=av; __syncthreads();
  for (int s=256;s>0;s>>=1){ if(t<s) red[t]=fmaxf(red[t],red[t+s]); __syncthreads(); }
  float mx = red[0]; __syncthreads();
  float e = (t < NB) ? __expf(av - mx) : 0.f;
  red[t]=e; __syncthreads();
  for (int s=256;s>0;s>>=1){ if(t<s) red[t]+=red[t+s]; __syncthreads(); }
  if (t < NB) wh[hh*NB + t] = e / red[0];
}

// softmax over h of adj[:,n] -> wo[n,h]
__global__ __launch_bounds__(64)
void smax_o_kernel(const float* __restrict__ adj, float* __restrict__ wo)
{
  const int n = blockIdx.x, t = threadIdx.x;
  float av = adj[t*NB + n];
  float mx = av;
  #pragma unroll
  for (int o=32;o>0;o>>=1) mx = fmaxf(mx, __shfl_xor(mx, o, 64));
  float e = __expf(av - mx);
  float s = e;
  #pragma unroll
  for (int o=32;o>0;o>>=1) s += __shfl_xor(s, o, 64);
  wo[n*64 + t] = e / s;
}

// mw_h[hh,c] = sum_n wh[hh,n]*relu(aoO[n,c]*sO[hh*NB+n, c])
__global__ __launch_bounds__(128)
void wredH_kernel(const float* __restrict__ wh, const float* __restrict__ ao,
                  const sb_t* __restrict__ s4, int colOff, sb_t* __restrict__ mw)
{
  const int hh = blockIdx.x;
  const int c = blockIdx.y*128 + threadIdx.x;
  const unsigned short* sp = (const unsigned short*)s4 + (size_t)hh*NB*4096 + colOff + c;
  const float* whp = wh + hh*NB;
  float acc = 0.f;
  for (int n=0; n<NB; ++n)
    acc += whp[n] * fmaxf(ao[(size_t)n*1024 + c] * b2f(sp[(size_t)n*4096]), 0.f);
  stv(&mw[(size_t)hh*1024 + c], acc);
}

// mw_o[n,c] = sum_h wo[n,h]*relu(ahS[h,c]*sH[h*NB+n, c])
__global__ __launch_bounds__(128)
void wredO_kernel(const float* __restrict__ wo, const float* __restrict__ ah,
                  const sb_t* __restrict__ s4, int colOff, sb_t* __restrict__ mw)
{
  const int n = blockIdx.x;
  const int c = blockIdx.y*128 + threadIdx.x;
  const unsigned short* sp = (const unsigned short*)s4 + (size_t)n*4096 + colOff + c;
  const float* wop = wo + n*64;
  float acc = 0.f;
  for (int h=0; h<NH; ++h)
    acc += wop[h] * fmaxf(ah[(size_t)h*1024 + c] * b2f(sp[(size_t)h*NB*4096]), 0.f);
  stv(&mw[(size_t)n*1024 + c], acc);
}

static __device__ __forceinline__ float bsum(float v, float* red){
  const int t = threadIdx.x;
  red[t]=v; __syncthreads();
  for (int s=512;s>0;s>>=1){ if(t<s) red[t]+=red[t+s]; __syncthreads(); }
  float r = red[0]; __syncthreads();
  return r;
}

// x[row,:] = LN( x + relu(msg[row,:] + b3s) ) * g + b ; also bf16 mirror
__global__ __launch_bounds__(1024)
void ln_update_kernel(const float* __restrict__ msg, const float* __restrict__ b3s,
                      const in_t* __restrict__ g, const in_t* __restrict__ b,
                      float* __restrict__ x, sb_t* __restrict__ xb)
{
  __shared__ float red[1024];
  const int row = blockIdx.x, t = threadIdx.x;
  float val = x[(size_t)row*1024 + t] + fmaxf(msg[(size_t)row*1024 + t] + b3s[t], 0.f);
  float mean = bsum(val, red) * (1.0f/1024.0f);
  float d = val - mean;
  float var = bsum(d*d, red) * (1.0f/1024.0f);
  float y = d * rsqrtf(var + 1e-5f) * g[t] + b[t];
  x[(size_t)row*1024 + t] = y;
  stv(&xb[(size_t)row*1024 + t], y);
}

// ---------------- host-side launchers ----------------
template<int EPI, int RELU, typename TC>
static inline void launch_mfma(hipStream_t st, int M, int N, int KS, int lda, int ldb, int nz,
    const sb_t* A, const sb_t* Bt, const float* bias, TC* C, int ldc, int coff,
    long long strideCz, const float* Wadj, const float* ab3s, float* adjOut)
{
  dim3 g((unsigned)(M/128), (unsigned)(N/128), (unsigned)nz);
  hipLaunchKernelGGL((gemm_mfma<EPI,RELU,TC>), g, dim3(256), 0, st,
                     M,N,KS,lda,ldb,A,Bt,bias,C,ldc,coff,strideCz,Wadj,ab3s,adjOut);
}

template<int EPI, int RELU, typename TC>
static inline void launch_mfma256(hipStream_t st, int M, int N, int K, int lda, int ldb,
    const sb_t* A, const sb_t* Bt, const float* bias, TC* C, int ldc, int coff,
    const float* Wadj, const float* ab3s, float* adjOut)
{
  dim3 g((unsigned)(M/256), (unsigned)(N/256), 1);
  hipLaunchKernelGGL((gemm256<EPI,RELU,TC>), g, dim3(512), 0, st,
                     M,N,K,lda,ldb,A,Bt,bias,C,ldc,coff,Wadj,ab3s,adjOut);
}

// split-K skinny GEMM: partials via EPI2 into scratch, then combineN -> f32 out
static inline void launch_skinny(hipStream_t st, int M, int N, int K, int lda, int ldb, int nz,
    const sb_t* A, const sb_t* Bt, const float* bias, float* outp, int relu, float* scratch)
{
  launch_mfma<2,0,float>(st, M, N, K/nz, lda, ldb, nz, A, Bt, nullptr, scratch, N, 0,
                         (long long)M*N, nullptr, nullptr, nullptr);
  hipLaunchKernelGGL((combineN_kernel<float>), dim3((unsigned)((M*N)/256)), dim3(256), 0, st,
                     scratch, (long long)M*N, nz, bias, N, relu, outp);
}

extern "C" void kernel_launch(void* const* d_in, const int* in_sizes, int n_in,
                              void* d_out, int out_size, void* d_ws, size_t ws_size,
                              hipStream_t stream)
{
  (void)in_sizes; (void)n_in; (void)out_size; (void)ws_size;

  const in_t* box  = (const in_t*)d_in[0];
  const in_t* spat = (const in_t*)d_in[1];
  const in_t* f3   = (const in_t*)d_in[2];
  const in_t* Wb1  = (const in_t*)d_in[3];
  const in_t* Wb2  = (const in_t*)d_in[5];
  const in_t* Ws1  = (const in_t*)d_in[7];
  const in_t* Ws2  = (const in_t*)d_in[9];
  const in_t* Ws3  = (const in_t*)d_in[11];
  const in_t* Wadj = (const in_t*)d_in[13];
  const in_t* gh   = (const in_t*)d_in[15];
  const in_t* bh   = (const in_t*)d_in[16];
  const in_t* go   = (const in_t*)d_in[17];
  const in_t* bo   = (const in_t*)d_in[18];
  const in_t* A1   = (const in_t*)d_in[19];
  const in_t* A2   = (const in_t*)d_in[21];
  const in_t* A3   = (const in_t*)d_in[23];
  const in_t* G1   = (const in_t*)d_in[25];
  const in_t* G2   = (const in_t*)d_in[27];
  const in_t* G3   = (const in_t*)d_in[29];
  const in_t* S1   = (const in_t*)d_in[31];
  const in_t* S2   = (const in_t*)d_in[33];
  const in_t* S3   = (const in_t*)d_in[35];
  const in_t* O1   = (const in_t*)d_in[37];
  const in_t* O2   = (const in_t*)d_in[39];
  const in_t* O3   = (const in_t*)d_in[41];
  out_t* out = (out_t*)d_out;

  // ---- workspace ----
  char* wsb = (char*)d_ws;
  size_t off = 0;
  auto alloc = [&](size_t bytes)->void* {
    void* p = wsb + off; off += (bytes + 255) & ~(size_t)255; return p;
  };
  float* pool   = (float*)alloc((size_t)POOL_TOTAL*4);
  sb_t* Wb1T    = (sb_t*)alloc((size_t)1024*12544*2);
  sb_t* Wb2T    = (sb_t*)alloc((size_t)1024*1024*2);
  sb_t* Ws2T    = (sb_t*)alloc((size_t)256*128*2);
  sb_t* Ws3T    = (sb_t*)alloc((size_t)1024*256*2);
  sb_t* A3T     = (sb_t*)alloc((size_t)1024*1024*2);
  sb_t* O3T     = (sb_t*)alloc((size_t)1024*1024*2);
  sb_t* S3T     = (sb_t*)alloc((size_t)1024*1024*2);
  sb_t* G3T     = (sb_t*)alloc((size_t)1024*1024*2);
  sb_t* s2Tall  = (sb_t*)alloc((size_t)4096*1024*2);  // [A2|O2|S2|G2] rows
  sb_t* O1T     = (sb_t*)alloc((size_t)1024*1024*2);
  sb_t* S1T     = (sb_t*)alloc((size_t)1024*1024*2);
  sb_t* A1T     = (sb_t*)alloc((size_t)1024*2048*2);
  sb_t* boxb    = (sb_t*)alloc((size_t)NB*12544*2);
  float* encP   = (float*)alloc((size_t)7*NB*EDIM*4);  // split-K partials (11 MB)
  sb_t* encMidb = (sb_t*)alloc((size_t)NB*EDIM*2);
  float* oB     = (float*)alloc((size_t)NB*EDIM*4);
  sb_t* oBb     = (sb_t*)alloc((size_t)NB*EDIM*2);
  float* hB     = (float*)alloc((size_t)NH*EDIM*4);
  sb_t* hBb     = (sb_t*)alloc((size_t)128*EDIM*2);
  sb_t* sp1b    = (sb_t*)alloc((size_t)PAIRS*128*2);
  sb_t* sp2b    = (sb_t*)alloc((size_t)PAIRS*256*2);
  sb_t* spFb    = (sb_t*)alloc((size_t)PAIRS*EDIM*2); // aliased as mbuf later
  sb_t* mbuf    = spFb;
  sb_t* s4      = (sb_t*)alloc((size_t)PAIRS*4096*2); // [sA|sO|sS|sG]
  float* ahA    = (float*)alloc((size_t)128*EDIM*4);
  float* aoA    = (float*)alloc((size_t)NB*EDIM*4);
  float* aoO    = (float*)alloc((size_t)NB*EDIM*4);
  float* ahS    = (float*)alloc((size_t)128*EDIM*4);
  float* aGv    = (float*)alloc((size_t)EDIM*4);
  float* adj    = (float*)alloc((size_t)PAIRS*4);
  float* wh     = (float*)alloc((size_t)PAIRS*4);
  float* wo     = (float*)alloc((size_t)PAIRS*4);
  sb_t* mwH     = (sb_t*)alloc((size_t)128*EDIM*2);
  sb_t* mwO     = (sb_t*)alloc((size_t)NB*EDIM*2);
  float* hmsg   = (float*)alloc((size_t)128*EDIM*4);
  float* omsg   = (float*)alloc((size_t)NB*EDIM*4);

  // ---- prep ----
  Prep17 pp;
  const int prepIdx[17] = {4,6,8,10,12,20,22,26,28,32,34,38,40,24,30,36,42};
  for (int i=0;i<17;++i) pp.p[i] = (const in_t*)d_in[prepIdx[i]];
  hipLaunchKernelGGL(prep_kernel, dim3(17), dim3(256), 0, stream, pp, pool);
  hipLaunchKernelGGL(gfeat_kernel, dim3(256), dim3(64), 0, stream, f3, pool + POOL_GFEAT);

  hipLaunchKernelGGL(tcvt_kernel, dim3(196,16), dim3(256), 0, stream, Wb1, Wb1T, 12544, 1024);
  hipLaunchKernelGGL(tcvt_kernel, dim3(16,16),  dim3(256), 0, stream, Wb2, Wb2T, 1024, 1024);
  hipLaunchKernelGGL(tcvt_kernel, dim3(2,4),    dim3(256), 0, stream, Ws2, Ws2T, 128, 256);
  hipLaunchKernelGGL(tcvt_kernel, dim3(4,16),   dim3(256), 0, stream, Ws3, Ws3T, 256, 1024);
  hipLaunchKernelGGL(tcvt_kernel, dim3(16,16),  dim3(256), 0, stream, A3, A3T, 1024, 1024);
  hipLaunchKernelGGL(tcvt_kernel, dim3(16,16),  dim3(256), 0, stream, O3, O3T, 1024, 1024);
  hipLaunchKernelGGL(tcvt_kernel, dim3(16,16),  dim3(256), 0, stream, S3, S3T, 1024, 1024);
  hipLaunchKernelGGL(tcvt_kernel, dim3(16,16),  dim3(256), 0, stream, G3, G3T, 1024, 1024);

  hipLaunchKernelGGL(pack_kt_kernel, dim3(16,16), dim3(256), 0, stream, A2, s2Tall,            1024);
  hipLaunchKernelGGL(pack_kt_kernel, dim3(16,16), dim3(256), 0, stream, O2, s2Tall+1024*1024,  1024);
  hipLaunchKernelGGL(pack_kt_kernel, dim3(16,16), dim3(256), 0, stream, S2, s2Tall+2048*1024,  1024);
  hipLaunchKernelGGL(pack_kt_kernel, dim3(16,16), dim3(256), 0, stream, G2, s2Tall+3072*1024,  1024);
  hipLaunchKernelGGL(pack_kt_kernel, dim3(16,16), dim3(256), 0, stream, O1, O1T, 1024);
  hipLaunchKernelGGL(pack_kt_kernel, dim3(16,16), dim3(256), 0, stream, S1, S1T, 1024);
  hipLaunchKernelGGL(pack_kt_kernel, dim3(32,16), dim3(256), 0, stream, A1, A1T, 2048);

  hipLaunchKernelGGL(cvt_kernel, dim3((NB*12544)/256), dim3(256), 0, stream, box, boxb, NB*12544);

  // ---- enc: split-K box GEMM (KS=1792, z=7) + combine, then @Wb2 (split-K) ----
  launch_mfma<2,0,float>(stream, NB, EDIM, 1792, 12544, 12544, 7,
      boxb, Wb1T, nullptr, encP, EDIM, 0, (long long)NB*EDIM, nullptr, nullptr, nullptr);
  hipLaunchKernelGGL((combineN_kernel<sb_t>), dim3(NB*EDIM/256), dim3(256), 0, stream,
                     encP, (long long)NB*EDIM, 7, pool+POOL_BB1, EDIM, 1, encMidb);
  launch_skinny(stream, NB, EDIM, EDIM, EDIM, EDIM, 4,
      encMidb, Wb2T, pool+POOL_BB2, oB, 1, encP);
  hipLaunchKernelGGL(encpost_kernel, dim3(NB,4), dim3(256), 0, stream, oB, oBb, hB, hBb);

  // ---- spatial MLP ----
  {
    dim3 g((PAIRS+63)/64, 2, 1);
    hipLaunchKernelGGL((gemm_valu<sb_t>), g, dim3(256), 0, stream,
        PAIRS, 128, SPA, spat, SPA, Ws1, 128, 0, pool+POOL_BS1, sp1b, 128, 1);
  }
  launch_mfma<0,1,sb_t>(stream, PAIRS, 256, 128, 128, 128, 1,
      sp1b, Ws2T, pool+POOL_BS2, sp2b, 256, 0, 0, nullptr, nullptr, nullptr);
  launch_mfma256<0,1,sb_t>(stream, PAIRS, EDIM, 256, 256, 256,
      sp2b, Ws3T, pool+POOL_BS3, spFb, EDIM, 0, nullptr, nullptr, nullptr);

  // ---- fused s-precompute: s4 = spF @ [A2|O2|S2|G2] + b2  (N=4096) ----
  launch_mfma256<0,0,sb_t>(stream, PAIRS, 4096, EDIM, EDIM, EDIM,
      spFb, s2Tall, pool+POOL_B2ALL, s4, 4096, 0, nullptr, nullptr, nullptr);

  // ---- aG = gfeat @ G1 + Gb1 (single row) ----
  {
    dim3 g(1, 1, 16);
    hipLaunchKernelGGL((gemm_valu<float>), g, dim3(256), 0, stream,
        1, 64, 256, pool+POOL_GFEAT, 256, G1, 64, 16384, pool+POOL_GB1, aGv, EDIM, 0);
  }

  // ---- 2 message-passing iterations ----
  for (int it=0; it<2; ++it) {
    // A-path -> adj
    launch_skinny(stream, 128, EDIM, EDIM, EDIM, 2048, 8,
        hBb, A1T, pool+POOL_AB1, ahA, 0, encP);
    launch_skinny(stream, NB, EDIM, EDIM, EDIM, 2048, 4,
        oBb, A1T+1024, nullptr, aoA, 0, encP);
    hipLaunchKernelGGL(mmake_kernel, dim3(PAIRS), dim3(256), 0, stream,
                       ahA, 1, 1024, aoA, 1, s4, 4096, 0, mbuf);
    (void)hipMemsetAsync(adj, 0, (size_t)PAIRS*4, stream);
    launch_mfma256<1,0,float>(stream, PAIRS, EDIM, EDIM, EDIM, EDIM,
        mbuf, A3T, nullptr, (float*)nullptr, 0, 0, Wadj, pool+POOL_AB3S, adj);
    hipLaunchKernelGGL(smax_h_kernel, dim3(NH), dim3(512), 0, stream, adj, wh);
    hipLaunchKernelGGL(smax_o_kernel, dim3(NB), dim3(64), 0, stream, adj, wo);

    // O-path -> h update
    launch_skinny(stream, NB, EDIM, EDIM, EDIM, 1024, 4,
        oBb, O1T, pool+POOL_OB1, aoO, 0, encP);
    hipLaunchKernelGGL(wredH_kernel, dim3(NH,8), dim3(128), 0, stream,
                       wh, aoO, s4, 1024, mwH);
    launch_skinny(stream, 128, EDIM, EDIM, EDIM, 1024, 8,
        mwH, O3T, nullptr, hmsg, 0, encP);
    hipLaunchKernelGGL(ln_update_kernel, dim3(NH), dim3(1024), 0, stream,
                       hmsg, pool+POOL_OB3S, gh, bh, hB, hBb);

    // S-path -> o update (uses updated h)
    launch_skinny(stream, 128, EDIM, EDIM, EDIM, 1024, 8,
        hBb, S1T, pool+POOL_SB1, ahS, 0, encP);
    hipLaunchKernelGGL(wredO_kernel, dim3(NB,8), dim3(128), 0, stream,
                       wo, ahS, s4, 2048, mwO);
    launch_skinny(stream, NB, EDIM, EDIM, EDIM, 1024, 4,
        mwO, S3T, nullptr, omsg, 0, encP);
    hipLaunchKernelGGL(ln_update_kernel, dim3(NB), dim3(1024), 0, stream,
                       omsg, pool+POOL_SB3S, go, bo, oB, oBb);
  }

  // ---- final heads ----
  launch_skinny(stream, 128, EDIM, EDIM, EDIM, 2048, 8,
      hBb, A1T, pool+POOL_AB1, ahA, 0, encP);
  launch_skinny(stream, NB, EDIM, EDIM, EDIM, 2048, 4,
      oBb, A1T+1024, nullptr, aoA, 0, encP);
  hipLaunchKernelGGL(mmake_kernel, dim3(PAIRS), dim3(256), 0, stream,
                     ahA, 1, 1024, aoA, 1, s4, 4096, 0, mbuf);
  launch_mfma256<0,1,out_t>(stream, PAIRS, EDIM, EDIM, EDIM, EDIM,
      mbuf, A3T, pool+POOL_AB3S, out, 2048, 0, nullptr, nullptr, nullptr);

  hipLaunchKernelGGL(mmake_kernel, dim3(PAIRS), dim3(256), 0, stream,
                     aGv, 1, 0, nullptr, 0, s4, 4096, 3072, mbuf);
  launch_mfma256<0,1,out_t>(stream, PAIRS, EDIM, EDIM, EDIM, EDIM,
      mbuf, G3T, pool+POOL_GB3S, out, 2048, 1024, nullptr, nullptr, nullptr);
}

// Round 7
// 1453.789 us; speedup vs baseline: 1.0197x; 1.0197x over previous
//
#include <hip/hip_runtime.h>
#include <hip/hip_bf16.h>
#include <cstdint>
#include <cstddef>

// ---------------- problem constants ----------------
#define NH    64
#define NB    384
#define EDIM  1024
#define PAIRS (NH*NB)   // 24576
#define SPA   36

using in_t  = float;
using out_t = float;
using sb_t  = __hip_bfloat16;

typedef short bf16x8 __attribute__((ext_vector_type(8)));
typedef float f32x4  __attribute__((ext_vector_type(4)));

static __device__ __forceinline__ float cvt(float x){ return x; }
static __device__ __forceinline__ float cvt(__hip_bfloat16 x){ return __bfloat162float(x); }
static __device__ __forceinline__ void stv(float* p, float v){ *p = v; }
static __device__ __forceinline__ void stv(__hip_bfloat16* p, float v){ *p = __float2bfloat16(v); }

static __device__ __forceinline__ float b2f(unsigned short u){
  union { unsigned int i; float f; } x; x.i = ((unsigned int)u)<<16; return x.f;
}

typedef const __attribute__((address_space(1))) void* as1_t;
typedef __attribute__((address_space(3))) void* as3_t;
static __device__ __forceinline__ void gl_lds16(const void* g, void* l){
  __builtin_amdgcn_global_load_lds((as1_t)g, (as3_t)l, 16, 0, 0);
}

// ---------------- bias/constant pool layout (floats) ----------------
#define POOL_BB1   0
#define POOL_BB2   1024
#define POOL_BS1   2048
#define POOL_BS2   2176
#define POOL_BS3   2432
#define POOL_AB1   3456
#define POOL_GB1   4480
#define POOL_SB1   5504
#define POOL_OB1   6528
#define POOL_B2ALL 7552          // 4096: [AB2|OB2|SB2|GB2]
#define POOL_AB3S  11648
#define POOL_GB3S  12672
#define POOL_SB3S  13696
#define POOL_OB3S  14720
#define POOL_GFEAT 15744
#define POOL_TOTAL 16000

// ============================================================================
// MFMA bf16 GEMM, 128x128 tile, BK=64 (two 32-wide sub-tiles), 4 waves.
// (kept for small/odd shapes; EPI2 = split-K partial writer)
// ============================================================================
template<int EPI, int RELU, typename TC>
__global__ __launch_bounds__(256)
void gemm_mfma(int M, int N, int KS, int lda, int ldb,
               const sb_t* __restrict__ A,
               const sb_t* __restrict__ Bt,
               const float* __restrict__ bias,
               TC* __restrict__ C, int ldc, int coff, long long strideCz,
               const float* __restrict__ Wadj,
               const float* __restrict__ ab3s,
               float* __restrict__ adjOut)
{
  __shared__ alignas(16) short lA[2][128*32];
  __shared__ alignas(16) short lB[2][128*32];
  const int tid = threadIdx.x;
  const int w = tid >> 6, l = tid & 63;
  const int m0 = blockIdx.x * 128, n0 = blockIdx.y * 128;
  const int wr = w >> 1, wc = w & 1;
  const int Koff = blockIdx.z * KS;

  const int srow = w*32 + (l>>2);
  const int scol = (l&3)*8;
  const sb_t* gA = A  + (size_t)(m0 + srow)*(size_t)lda + Koff + scol;
  const sb_t* gB = Bt + (size_t)(n0 + srow)*(size_t)ldb + Koff + scol;
  short* lA0 = &lA[0][(w*32)*32];
  short* lA1 = &lA[1][(w*32)*32];
  short* lB0 = &lB[0][(w*32)*32];
  short* lB1 = &lB[1][(w*32)*32];

  f32x4 acc[4][4];
  const f32x4 zz = {0.f,0.f,0.f,0.f};
  #pragma unroll
  for (int i=0;i<4;++i)
    #pragma unroll
    for (int j=0;j<4;++j) acc[i][j] = zz;

  const int fr  = l & 15;
  const int fko = (l >> 4) * 8;

  for (int k0 = 0; k0 < KS; k0 += 64) {
    gl_lds16(gA + k0,               lA0);
    gl_lds16(gA + k0 + 16*lda,      lA0 + 16*32);
    gl_lds16(gA + k0 + 32,          lA1);
    gl_lds16(gA + k0 + 32 + 16*lda, lA1 + 16*32);
    gl_lds16(gB + k0,               lB0);
    gl_lds16(gB + k0 + 16*ldb,      lB0 + 16*32);
    gl_lds16(gB + k0 + 32,          lB1);
    gl_lds16(gB + k0 + 32 + 16*ldb, lB1 + 16*32);
    __syncthreads();
    #pragma unroll
    for (int kh=0; kh<2; ++kh) {
      bf16x8 af[4], bfv[4];
      #pragma unroll
      for (int i=0;i<4;++i)
        af[i]  = *(const bf16x8*)&lA[kh][(wr*64 + i*16 + fr)*32 + fko];
      #pragma unroll
      for (int j=0;j<4;++j)
        bfv[j] = *(const bf16x8*)&lB[kh][(wc*64 + j*16 + fr)*32 + fko];
      #pragma unroll
      for (int i=0;i<4;++i)
        #pragma unroll
        for (int j=0;j<4;++j)
          acc[i][j] = __builtin_amdgcn_mfma_f32_16x16x32_bf16(af[i], bfv[j], acc[i][j], 0, 0, 0);
    }
    __syncthreads();
  }

  const int cn = l & 15;
  const int cr = (l >> 4) * 4;

  if (EPI == 1) {
    float part[4][4];
    #pragma unroll
    for (int i=0;i<4;++i)
      #pragma unroll
      for (int r=0;r<4;++r) part[i][r] = 0.f;
    #pragma unroll
    for (int j=0;j<4;++j) {
      const int col = n0 + wc*64 + j*16 + cn;
      const float wv = Wadj[col];
      const float bv = ab3s[col];
      #pragma unroll
      for (int i=0;i<4;++i)
        #pragma unroll
        for (int r=0;r<4;++r)
          part[i][r] += fmaxf(acc[i][j][r] + bv, 0.f) * wv;
    }
    #pragma unroll
    for (int m=1;m<16;m<<=1)
      #pragma unroll
      for (int i=0;i<4;++i)
        #pragma unroll
        for (int r=0;r<4;++r)
          part[i][r] += __shfl_xor(part[i][r], m, 64);
    if (cn == 0) {
      #pragma unroll
      for (int i=0;i<4;++i)
        #pragma unroll
        for (int r=0;r<4;++r)
          atomicAdd(&adjOut[m0 + wr*64 + i*16 + cr + r], part[i][r]);
    }
    return;
  }

  #pragma unroll
  for (int j=0;j<4;++j) {
    const int col = n0 + wc*64 + j*16 + cn;
    const float bv = (EPI==0 && bias) ? bias[col] : 0.f;
    #pragma unroll
    for (int i=0;i<4;++i) {
      #pragma unroll
      for (int r=0;r<4;++r) {
        const int row = m0 + wr*64 + i*16 + cr + r;
        float v = acc[i][j][r] + bv;
        if (RELU) v = fmaxf(v, 0.f);
        if (EPI == 2)
          stv(&C[(size_t)blockIdx.z*strideCz + (size_t)row*ldc + col], v);
        else
          stv(&C[(size_t)row*ldc + coff + col], v);
      }
    }
  }
}

// ============================================================================
// 256x256 8-phase MFMA GEMM, 16x16x32 MFMA, SINGLE-BARRIER phases (r7).
// Correctness audit: the phase-end barrier alone separates "all waves drained
// reads of region R" (each wave's lgkmcnt(0) precedes its barrier arrival)
// from "stage() overwrites R" (issued only after that barrier). Verified for
// S3 (prior-tile A rows, drained before prior P4-end bar), S0/S1 (B read
// wholly in P1, drained in P1), S2 (A ph0/ph1 rows, drained in P1/P2).
// T1 XCD-swizzle, T2 LDS XOR-swizzle (chunk ^= row&7), T3/T4 counted vmcnt(6),
// T5 setprio. C = A[M,K] @ Bt[N,K]^T ; M%256==0, N%256==0, K%64==0, K>=128.
// Epilogue: C staged through 128 KiB LDS (chunk-XOR swizzled) + NONTEMPORAL
// 16B global stores (keep the 196MB C stream out of L2 so A/B panels stay).
// ============================================================================
template<int EPI, int RELU, typename TC>
__global__ __launch_bounds__(512, 2)
void gemm256(int M, int N, int K, int lda, int ldb,
             const sb_t* __restrict__ A,
             const sb_t* __restrict__ Bt,
             const float* __restrict__ bias,
             TC* __restrict__ C, int ldc, int coff,
             const float* __restrict__ Wadj,
             const float* __restrict__ ab3s,
             float* __restrict__ adjOut)
{
  __shared__ alignas(16) short sh[2][2][256*64];   // [buf][0=A,1=B], 128 KiB

  const int tid = threadIdx.x;
  const int w = tid >> 6, l = tid & 63;
  const int wr = w >> 2, wc = w & 3;

  // T1: XCD-chunked bijective swizzle, y-fastest within chunk.
  const unsigned gx = gridDim.x, gy = gridDim.y;
  const unsigned nwg = gx * gy;
  const unsigned hwid = blockIdx.x + gx * blockIdx.y;
  const unsigned q = nwg >> 3, rr = nwg & 7;
  const unsigned xcd = hwid & 7, jj = hwid >> 3;
  const unsigned wg = (xcd < rr ? xcd*(q+1) : rr*(q+1) + (xcd-rr)*q) + jj;
  const int by = (int)(wg % gy), bx = (int)(wg / gy);
  const int m0 = bx * 256, n0 = by * 256;

  const int NT = K >> 6;

  // staging: lane l covers row (l>>3), dest chunk (l&7); source pre-swizzled.
  const int lr = l >> 3;
  const int lch = ((l & 7) ^ lr) * 8;

  auto stage = [&](int p, int s, int t){
    short* lbA = &sh[p][0][0];
    short* lbB = &sh[p][1][0];
    const int k0 = t * 64;
    #pragma unroll
    for (int c=0;c<2;++c){
      const int g = (w<<1) + c;          // 0..15, wave-uniform
      int row0; const sb_t* mat; int ld; int rb; short* dst;
      if (s==0){ row0 = g*8;                              mat=Bt; ld=ldb; rb=n0; dst=lbB; }
      else if (s==1){ row0 = 128 + g*8;                   mat=Bt; ld=ldb; rb=n0; dst=lbB; }
      else if (s==2){ row0 = (g<8)? g*8    : 128+(g-8)*8; mat=A;  ld=lda; rb=m0; dst=lbA; }
      else          { row0 = (g<8)? 64+g*8 : 192+(g-8)*8; mat=A;  ld=lda; rb=m0; dst=lbA; }
      gl_lds16(mat + (size_t)(rb + row0 + lr)*(size_t)ld + k0 + lch, dst + row0*64);
    }
  };

  // fragment-read per-lane constants (16x16x32 layout)
  const int fr = l & 15;
  const int fg = l >> 4;
  const int sx = fr & 7;
  const int x0 = ((0 + fg) ^ sx) * 8;    // kk=0 swizzled chunk (shorts)
  const int x1 = ((4 + fg) ^ sx) * 8;    // kk=1
  const int oA = (wr*128 + fr) * 64;
  const int oB = (wc*64  + fr) * 64;

  f32x4 acc[8][4];
  const f32x4 zz = {0.f,0.f,0.f,0.f};
  #pragma unroll
  for (int i=0;i<8;++i)
    #pragma unroll
    for (int j=0;j<4;++j) acc[i][j] = zz;

#define G256_BAR()   __builtin_amdgcn_s_barrier()
#define G256_LGKM(n) asm volatile("s_waitcnt lgkmcnt(" #n ")" ::: "memory")
#define G256_VM(n)   asm volatile("s_waitcnt vmcnt(" #n ")" ::: "memory")
#define G256_LOADA(ph)                                                   \
  af[0][0] = *(const bf16x8*)(sa + oA + (2*(ph)+0)*1024 + x0);           \
  af[0][1] = *(const bf16x8*)(sa + oA + (2*(ph)+0)*1024 + x1);           \
  af[1][0] = *(const bf16x8*)(sa + oA + (2*(ph)+1)*1024 + x0);           \
  af[1][1] = *(const bf16x8*)(sa + oA + (2*(ph)+1)*1024 + x1)
#define G256_MFMA(ph)                                                    \
  do { __builtin_amdgcn_s_setprio(1);                                    \
    _Pragma("unroll") for (int kk=0; kk<2; ++kk)                         \
    _Pragma("unroll") for (int ii=0; ii<2; ++ii)                         \
    _Pragma("unroll") for (int j=0; j<4; ++j)                            \
      acc[2*(ph)+ii][j] = __builtin_amdgcn_mfma_f32_16x16x32_bf16(       \
          af[ii][kk], bf[j][kk], acc[2*(ph)+ii][j], 0, 0, 0);            \
    __builtin_amdgcn_s_setprio(0); } while(0)

  // ---- prologue: tile0 S0..S3, vm(4), tile1 S0..S2, vm(6) ----
  stage(0,0,0); stage(0,1,0); stage(0,2,0); stage(0,3,0);
  G256_VM(4);
  if (NT > 1) {
    stage(1,0,1); stage(1,1,1); stage(1,2,1);
    G256_VM(6);
  } else {
    G256_VM(0);
  }
  G256_BAR();

  for (int t=0; t<NT; ++t) {
    const int cur = t & 1, pn = cur ^ 1;
    short* sa  = &sh[cur][0][0];
    short* sb2 = &sh[cur][1][0];
    bf16x8 bf[4][2], af[2][2];

    // ---- P1: reads B(8)+A0(4), stage S3(t+1), lgkm0, MFMA0, bar ----
    #pragma unroll
    for (int j=0;j<4;++j){
      bf[j][0] = *(const bf16x8*)(sb2 + oB + j*1024 + x0);
      bf[j][1] = *(const bf16x8*)(sb2 + oB + j*1024 + x1);
    }
    G256_LOADA(0);
    if (t+1 < NT) stage(pn, 3, t+1);
    G256_LGKM(0);
    G256_MFMA(0);
    G256_BAR();

    // ---- P2 ----
    G256_LOADA(1);
    if (t+2 < NT) stage(cur, 0, t+2);
    G256_LGKM(0);
    G256_MFMA(1);
    G256_BAR();

    // ---- P3 ----
    G256_LOADA(2);
    if (t+2 < NT) stage(cur, 1, t+2);
    G256_LGKM(0);
    G256_MFMA(2);
    G256_BAR();

    // ---- P4 ----
    G256_LOADA(3);
    if (t+2 < NT) stage(cur, 2, t+2);
    G256_LGKM(0);
    G256_MFMA(3);
    if (t+1 < NT) {
      if (t+2 < NT) { G256_VM(6); } else { G256_VM(0); }
    }
    G256_BAR();
  }

#undef G256_LOADA
#undef G256_MFMA

  // ---- epilogue ----
  const int cn = l & 15;
  const int cr = (l >> 4) * 4;

  if (EPI == 1) {
    float part[8][4];
    #pragma unroll
    for (int i=0;i<8;++i)
      #pragma unroll
      for (int r=0;r<4;++r) part[i][r] = 0.f;
    #pragma unroll
    for (int j=0;j<4;++j) {
      const int col = n0 + wc*64 + j*16 + cn;
      const float wv = Wadj[col];
      const float bv = ab3s[col];
      #pragma unroll
      for (int i=0;i<8;++i)
        #pragma unroll
        for (int r=0;r<4;++r)
          part[i][r] += fmaxf(acc[i][j][r] + bv, 0.f) * wv;
    }
    #pragma unroll
    for (int m=1;m<16;m<<=1)
      #pragma unroll
      for (int i=0;i<8;++i)
        #pragma unroll
        for (int r=0;r<4;++r)
          part[i][r] += __shfl_xor(part[i][r], m, 64);
    if (cn == 0) {
      #pragma unroll
      for (int i=0;i<8;++i)
        #pragma unroll
        for (int r=0;r<4;++r)
          atomicAdd(&adjOut[m0 + wr*128 + i*16 + cr + r], part[i][r]);
    }
    return;
  }

  // EPI0: LDS-staged coalesced C store (chunk-XOR swizzled, nontemporal)
  if constexpr (sizeof(TC) == 2) {
    sb_t* ebs = (sb_t*)&sh[0][0][0];     // 256x256 bf16 = 128 KiB
    G256_LGKM(0);
    G256_BAR();
    #pragma unroll
    for (int i=0;i<8;++i){
      #pragma unroll
      for (int j=0;j<4;++j){
        const int lcol = wc*64 + j*16 + cn;
        const float bv = bias ? bias[n0 + lcol] : 0.f;
        const int cb = lcol >> 3, ce = lcol & 7;
        #pragma unroll
        for (int r=0;r<4;++r){
          const int lrow = wr*128 + i*16 + cr + r;
          float v = acc[i][j][r] + bv;
          if (RELU) v = fmaxf(v, 0.f);
          stv(&ebs[lrow*256 + ((cb ^ (lrow & 7)) << 3) + ce], v);
        }
      }
    }
    G256_LGKM(0);
    G256_BAR();
    #pragma unroll
    for (int p=0;p<16;++p){
      const int R = p*16 + (tid>>5);
      const int c = tid & 31;
      bf16x8 v = *(const bf16x8*)((const short*)ebs + R*256 + ((c ^ (R & 7)) << 3));
      __builtin_nontemporal_store(v,
          (bf16x8*)((short*)C + (size_t)(m0+R)*ldc + coff + n0 + c*8));
    }
  } else {
    // f32: two 128-row passes
    float* ebf = (float*)&sh[0][0][0];   // 128x256 f32 = 128 KiB
    #pragma unroll
    for (int h=0; h<2; ++h){
      G256_LGKM(0);
      G256_BAR();
      if (wr == h){
        #pragma unroll
        for (int i=0;i<8;++i){
          #pragma unroll
          for (int j=0;j<4;++j){
            const int lcol = wc*64 + j*16 + cn;
            const float bv = bias ? bias[n0 + lcol] : 0.f;
            const int cb = lcol >> 2, ce = lcol & 3;
            #pragma unroll
            for (int r=0;r<4;++r){
              const int lrow = i*16 + cr + r;
              float v = acc[i][j][r] + bv;
              if (RELU) v = fmaxf(v, 0.f);
              ebf[lrow*256 + ((cb ^ (lrow & 7)) << 2) + ce] = v;
            }
          }
        }
      }
      G256_LGKM(0);
      G256_BAR();
      #pragma unroll
      for (int p=0;p<16;++p){
        const int R = p*8 + (tid>>6);
        const int c = tid & 63;
        f32x4 v = *(const f32x4*)&ebf[R*256 + ((c ^ (R & 7)) << 2)];
        __builtin_nontemporal_store(v,
            (f32x4*)((float*)C + (size_t)(m0 + h*128 + R)*ldc + coff + n0 + c*4));
      }
    }
  }
#undef G256_BAR
#undef G256_LGKM
#undef G256_VM
}

// ============================================================================
// fp32 VALU GEMM (tiny/odd shapes: spatial 36->128, gfeat@G1)
// ============================================================================
template<typename TC>
__global__ __launch_bounds__(256)
void gemm_valu(int M, int N, int K,
               const in_t* __restrict__ S, int ldsS,
               const in_t* __restrict__ B, int ldb, long long strideB,
               const float* __restrict__ bias,
               TC* __restrict__ C, int ldc, int reluOut)
{
  __shared__ float As[16][65];
  __shared__ float Bs[16][68];
  const int z  = blockIdx.z;
  const in_t* Bz = B + (long long)z * strideB;
  const int m0 = blockIdx.x * 64;
  const int n0 = blockIdx.y * 64;
  const int tid = threadIdx.x;
  const int tx = tid & 15;
  const int ty = tid >> 4;

  float acc[4][4];
  #pragma unroll
  for (int i=0;i<4;++i)
    #pragma unroll
    for (int j=0;j<4;++j) acc[i][j]=0.f;

  const int kTiles = (K + 15) >> 4;
  for (int kt=0; kt<kTiles; ++kt) {
    const int k0 = kt << 4;
    #pragma unroll
    for (int q=0;q<4;++q) {
      const int p = m0 + ty + 16*q;
      const int c = k0 + tx;
      As[tx][ty+16*q] = (p < M && c < K) ? S[(size_t)p*ldsS + c] : 0.f;
    }
    {
      const int n = tid & 63;
      #pragma unroll
      for (int q=0;q<4;++q) {
        const int kk = (tid >> 6) + 4*q;
        const int gk = k0 + kk;
        const int gn = n0 + n;
        Bs[kk][n] = (gk < K && gn < N) ? Bz[(size_t)gk*ldb + gn] : 0.f;
      }
    }
    __syncthreads();
    #pragma unroll
    for (int kk=0; kk<16; ++kk) {
      float a[4], b[4];
      #pragma unroll
      for (int i=0;i<4;++i) a[i] = As[kk][ty + 16*i];
      #pragma unroll
      for (int j=0;j<4;++j) b[j] = Bs[kk][tx + 16*j];
      #pragma unroll
      for (int i=0;i<4;++i)
        #pragma unroll
        for (int j=0;j<4;++j) acc[i][j] += a[i]*b[j];
    }
    __syncthreads();
  }
  #pragma unroll
  for (int i=0;i<4;++i) {
    const int r = m0 + ty + 16*i;
    if (r >= M) continue;
    #pragma unroll
    for (int j=0;j<4;++j) {
      const int nn = n0 + tx + 16*j;
      if (nn >= N) continue;
      const int ccol = z*N + nn;
      float v = acc[i][j];
      if (bias) v += bias[ccol];
      if (reluOut) v = fmaxf(v, 0.f);
      stv(&C[(size_t)r*ldc + ccol], v);
    }
  }
}

// ============================================================================
// prep kernels
// ============================================================================
struct Prep17 { const in_t* p[17]; };

__global__ __launch_bounds__(256)
void prep_kernel(Prep17 a, float* __restrict__ pool)
{
  const int len[17] = {1024,1024,128,256,1024,1024,1024,1024,1024,1024,1024,1024,1024,
                       1024,1024,1024,1024};
  const int off[17] = {POOL_BB1,POOL_BB2,POOL_BS1,POOL_BS2,POOL_BS3,POOL_AB1,
                       POOL_B2ALL+0,      // AB2
                       POOL_GB1,
                       POOL_B2ALL+3072,   // GB2
                       POOL_SB1,
                       POOL_B2ALL+2048,   // SB2
                       POOL_OB1,
                       POOL_B2ALL+1024,   // OB2
                       POOL_AB3S,POOL_GB3S,POOL_SB3S,POOL_OB3S};
  const int j = blockIdx.x;
  const in_t* src = a.p[j];
  const int L = len[j], o = off[j];
  for (int i = threadIdx.x; i < L; i += blockDim.x) {
    if (j < 13) {
      pool[o+i] = src[i];
    } else {
      float s = 0.f;
      for (int k=0;k<16;++k) s += src[k*1024 + i];
      pool[o+i] = s;
    }
  }
}

__global__ __launch_bounds__(64)
void gfeat_kernel(const in_t* __restrict__ f3, float* __restrict__ g)
{
  const int c = blockIdx.x;
  const int t = threadIdx.x;
  float s = (t < 49) ? f3[c*49 + t] : 0.f;
  #pragma unroll
  for (int o=32;o>0;o>>=1) s += __shfl_down(s, o, 64);
  if (t == 0) g[c] = s * (1.0f/49.0f);
}

// f32 (R x C) -> bf16 (C x R)
__global__ __launch_bounds__(256)
void tcvt_kernel(const float* __restrict__ in, sb_t* __restrict__ outT, int R, int C)
{
  __shared__ float t[64][65];
  const int r0 = blockIdx.x*64, c0 = blockIdx.y*64;
  const int x = threadIdx.x & 63, y = threadIdx.x >> 6;
  #pragma unroll 4
  for (int q=0;q<16;++q){ const int rl = q*4 + y; t[rl][x] = in[(size_t)(r0+rl)*C + c0 + x]; }
  __syncthreads();
  #pragma unroll 4
  for (int q=0;q<16;++q){ const int cl = q*4 + y; stv(&outT[(size_t)(c0+cl)*R + r0 + x], t[x][cl]); }
}

// W (16, Cdim, 64) f32 -> PT[k*64+u][c] bf16
__global__ __launch_bounds__(256)
void pack_kt_kernel(const float* __restrict__ W, sb_t* __restrict__ PT, int Cdim)
{
  __shared__ float t[64][65];
  const int c0 = blockIdx.x*64; const int k = blockIdx.y;
  const int x = threadIdx.x & 63, y = threadIdx.x >> 6;
  #pragma unroll 4
  for (int q=0;q<16;++q){ const int cl = q*4 + y; t[cl][x] = W[((size_t)k*Cdim + c0 + cl)*64 + x]; }
  __syncthreads();
  #pragma unroll 4
  for (int q=0;q<16;++q){ const int u = q*4 + y; stv(&PT[((size_t)k*64 + u)*Cdim + c0 + x], t[x][u]); }
}

__global__ void cvt_kernel(const float* __restrict__ in, sb_t* __restrict__ o, int n){
  const int i = blockIdx.x*256 + threadIdx.x;
  if (i < n) stv(&o[i], in[i]);
}

// generic split-K combine: out[i] = (relu?)( sum_z part[z*stride+i] + bias[i&(N-1)] )
template<typename TO>
__global__ __launch_bounds__(256)
void combineN_kernel(const float* __restrict__ part, long long stride, int nz,
                     const float* __restrict__ bias, int N, int relu,
                     TO* __restrict__ out)
{
  const int i = blockIdx.x*256 + threadIdx.x;
  float v = bias ? bias[i & (N-1)] : 0.f;
  for (int z=0; z<nz; ++z) v += part[(long long)z*stride + i];
  if (relu) v = fmaxf(v, 0.f);
  stv(&out[i], v);
}

// enc fp32 -> bf16 mirror + h fp32/bf16 copies
__global__ __launch_bounds__(256)
void encpost_kernel(const float* __restrict__ oB, sb_t* __restrict__ oBb,
                    float* __restrict__ hB, sb_t* __restrict__ hBb)
{
  const int p = blockIdx.x; const int c = blockIdx.y*256 + threadIdx.x;
  const float v = oB[(size_t)p*1024 + c];
  stv(&oBb[(size_t)p*1024+c], v);
  if (p < NH){ hB[(size_t)p*1024+c] = v; stv(&hBb[(size_t)p*1024+c], v); }
}

// m[p,c] = bf16( relu( (U[p/NB,c] + V[p%NB,c]) * S4[p, colOff+c] ) )
__global__ __launch_bounds__(256)
void mmake_kernel(const float* __restrict__ U, int hasU, int ldu,
                  const float* __restrict__ V, int hasV,
                  const sb_t* __restrict__ S, int ldS, int colOff,
                  sb_t* __restrict__ Mo)
{
  const int p = blockIdx.x;
  const int c = threadIdx.x * 4;
  const ushort4 sv = *(const ushort4*)((const unsigned short*)S + (size_t)p*ldS + colOff + c);
  float a0=0.f,a1=0.f,a2=0.f,a3=0.f;
  if (hasU){ const float* Up = U + (size_t)(p/NB)*ldu + c; a0=Up[0];a1=Up[1];a2=Up[2];a3=Up[3]; }
  if (hasV){ const float* Vp = V + (size_t)(p%NB)*1024 + c; a0+=Vp[0];a1+=Vp[1];a2+=Vp[2];a3+=Vp[3]; }
  __hip_bfloat16* mo = (__hip_bfloat16*)Mo + (size_t)p*1024 + c;
  mo[0] = __float2bfloat16(fmaxf(a0*b2f(sv.x),0.f));
  mo[1] = __float2bfloat16(fmaxf(a1*b2f(sv.y),0.f));
  mo[2] = __float2bfloat16(fmaxf(a2*b2f(sv.z),0.f));
  mo[3] = __float2bfloat16(fmaxf(a3*b2f(sv.w),0.f));
}

// softmax over n of adj[hh,:] -> wh[hh,n]
__global__ __launch_bounds__(512)
void smax_h_kernel(const float* __restrict__ adj, float* __restrict__ wh)
{
  __shared__ float red[512];
  const int hh = blockIdx.x, t = threadIdx.x;
  float av = (t < NB) ? adj[hh*NB + t] : -1e30f;
  red[t]=av; __syncthreads();
  for (int s=256;s>0;s>>=1){ if(t<s) red[t]=fmaxf(red[t],red[t+s]); __syncthreads(); }
  float mx = red[0]; __syncthreads();
  float e = (t < NB) ? __expf(av - mx) : 0.f;
  red[t]=e; __syncthreads();
  for (int s=256;s>0;s>>=1){ if(t<s) red[t]+=red[t+s]; __syncthreads(); }
  if (t < NB) wh[hh*NB + t] = e / red[0];
}

// softmax over h of adj[:,n] -> wo[n,h]
__global__ __launch_bounds__(64)
void smax_o_kernel(const float* __restrict__ adj, float* __restrict__ wo)
{
  const int n = blockIdx.x, t = threadIdx.x;
  float av = adj[t*NB + n];
  float mx = av;
  #pragma unroll
  for (int o=32;o>0;o>>=1) mx = fmaxf(mx, __shfl_xor(mx, o, 64));
  float e = __expf(av - mx);
  float s = e;
  #pragma unroll
  for (int o=32;o>0;o>>=1) s += __shfl_xor(s, o, 64);
  wo[n*64 + t] = e / s;
}

// mw_h[hh,c] = sum_n wh[hh,n]*relu(aoO[n,c]*sO[hh*NB+n, c])
__global__ __launch_bounds__(128)
void wredH_kernel(const float* __restrict__ wh, const float* __restrict__ ao,
                  const sb_t* __restrict__ s4, int colOff, sb_t* __restrict__ mw)
{
  const int hh = blockIdx.x;
  const int c = blockIdx.y*128 + threadIdx.x;
  const unsigned short* sp = (const unsigned short*)s4 + (size_t)hh*NB*4096 + colOff + c;
  const float* whp = wh + hh*NB;
  float acc = 0.f;
  for (int n=0; n<NB; ++n)
    acc += whp[n] * fmaxf(ao[(size_t)n*1024 + c] * b2f(sp[(size_t)n*4096]), 0.f);
  stv(&mw[(size_t)hh*1024 + c], acc);
}

// mw_o[n,c] = sum_h wo[n,h]*relu(ahS[h,c]*sH[h*NB+n, c])
__global__ __launch_bounds__(128)
void wredO_kernel(const float* __restrict__ wo, const float* __restrict__ ah,
                  const sb_t* __restrict__ s4, int colOff, sb_t* __restrict__ mw)
{
  const int n = blockIdx.x;
  const int c = blockIdx.y*128 + threadIdx.x;
  const unsigned short* sp = (const unsigned short*)s4 + (size_t)n*4096 + colOff + c;
  const float* wop = wo + n*64;
  float acc = 0.f;
  for (int h=0; h<NH; ++h)
    acc += wop[h] * fmaxf(ah[(size_t)h*1024 + c] * b2f(sp[(size_t)h*NB*4096]), 0.f);
  stv(&mw[(size_t)n*1024 + c], acc);
}

static __device__ __forceinline__ float bsum(float v, float* red){
  const int t = threadIdx.x;
  red[t]=v; __syncthreads();
  for (int s=512;s>0;s>>=1){ if(t<s) red[t]+=red[t+s]; __syncthreads(); }
  float r = red[0]; __syncthreads();
  return r;
}

// x[row,:] = LN( x + relu(msg[row,:] + b3s) ) * g + b ; also bf16 mirror
__global__ __launch_bounds__(1024)
void ln_update_kernel(const float* __restrict__ msg, const float* __restrict__ b3s,
                      const in_t* __restrict__ g, const in_t* __restrict__ b,
                      float* __restrict__ x, sb_t* __restrict__ xb)
{
  __shared__ float red[1024];
  const int row = blockIdx.x, t = threadIdx.x;
  float val = x[(size_t)row*1024 + t] + fmaxf(msg[(size_t)row*1024 + t] + b3s[t], 0.f);
  float mean = bsum(val, red) * (1.0f/1024.0f);
  float d = val - mean;
  float var = bsum(d*d, red) * (1.0f/1024.0f);
  float y = d * rsqrtf(var + 1e-5f) * g[t] + b[t];
  x[(size_t)row*1024 + t] = y;
  stv(&xb[(size_t)row*1024 + t], y);
}

// ---------------- host-side launchers ----------------
template<int EPI, int RELU, typename TC>
static inline void launch_mfma(hipStream_t st, int M, int N, int KS, int lda, int ldb, int nz,
    const sb_t* A, const sb_t* Bt, const float* bias, TC* C, int ldc, int coff,
    long long strideCz, const float* Wadj, const float* ab3s, float* adjOut)
{
  dim3 g((unsigned)(M/128), (unsigned)(N/128), (unsigned)nz);
  hipLaunchKernelGGL((gemm_mfma<EPI,RELU,TC>), g, dim3(256), 0, st,
                     M,N,KS,lda,ldb,A,Bt,bias,C,ldc,coff,strideCz,Wadj,ab3s,adjOut);
}

template<int EPI, int RELU, typename TC>
static inline void launch_mfma256(hipStream_t st, int M, int N, int K, int lda, int ldb,
    const sb_t* A, const sb_t* Bt, const float* bias, TC* C, int ldc, int coff,
    const float* Wadj, const float* ab3s, float* adjOut)
{
  dim3 g((unsigned)(M/256), (unsigned)(N/256), 1);
  hipLaunchKernelGGL((gemm256<EPI,RELU,TC>), g, dim3(512), 0, st,
                     M,N,K,lda,ldb,A,Bt,bias,C,ldc,coff,Wadj,ab3s,adjOut);
}

// split-K skinny GEMM: partials via EPI2 into scratch, then combineN -> f32 out
static inline void launch_skinny(hipStream_t st, int M, int N, int K, int lda, int ldb, int nz,
    const sb_t* A, const sb_t* Bt, const float* bias, float* outp, int relu, float* scratch)
{
  launch_mfma<2,0,float>(st, M, N, K/nz, lda, ldb, nz, A, Bt, nullptr, scratch, N, 0,
                         (long long)M*N, nullptr, nullptr, nullptr);
  hipLaunchKernelGGL((combineN_kernel<float>), dim3((unsigned)((M*N)/256)), dim3(256), 0, st,
                     scratch, (long long)M*N, nz, bias, N, relu, outp);
}

extern "C" void kernel_launch(void* const* d_in, const int* in_sizes, int n_in,
                              void* d_out, int out_size, void* d_ws, size_t ws_size,
                              hipStream_t stream)
{
  (void)in_sizes; (void)n_in; (void)out_size; (void)ws_size;

  const in_t* box  = (const in_t*)d_in[0];
  const in_t* spat = (const in_t*)d_in[1];
  const in_t* f3   = (const in_t*)d_in[2];
  const in_t* Wb1  = (const in_t*)d_in[3];
  const in_t* Wb2  = (const in_t*)d_in[5];
  const in_t* Ws1  = (const in_t*)d_in[7];
  const in_t* Ws2  = (const in_t*)d_in[9];
  const in_t* Ws3  = (const in_t*)d_in[11];
  const in_t* Wadj = (const in_t*)d_in[13];
  const in_t* gh   = (const in_t*)d_in[15];
  const in_t* bh   = (const in_t*)d_in[16];
  const in_t* go   = (const in_t*)d_in[17];
  const in_t* bo   = (const in_t*)d_in[18];
  const in_t* A1   = (const in_t*)d_in[19];
  const in_t* A2   = (const in_t*)d_in[21];
  const in_t* A3   = (const in_t*)d_in[23];
  const in_t* G1   = (const in_t*)d_in[25];
  const in_t* G2   = (const in_t*)d_in[27];
  const in_t* G3   = (const in_t*)d_in[29];
  const in_t* S1   = (const in_t*)d_in[31];
  const in_t* S2   = (const in_t*)d_in[33];
  const in_t* S3   = (const in_t*)d_in[35];
  const in_t* O1   = (const in_t*)d_in[37];
  const in_t* O2   = (const in_t*)d_in[39];
  const in_t* O3   = (const in_t*)d_in[41];
  out_t* out = (out_t*)d_out;

  // ---- workspace ----
  char* wsb = (char*)d_ws;
  size_t off = 0;
  auto alloc = [&](size_t bytes)->void* {
    void* p = wsb + off; off += (bytes + 255) & ~(size_t)255; return p;
  };
  float* pool   = (float*)alloc((size_t)POOL_TOTAL*4);
  sb_t* Wb1T    = (sb_t*)alloc((size_t)1024*12544*2);
  sb_t* Wb2T    = (sb_t*)alloc((size_t)1024*1024*2);
  sb_t* Ws2T    = (sb_t*)alloc((size_t)256*128*2);
  sb_t* Ws3T    = (sb_t*)alloc((size_t)1024*256*2);
  sb_t* A3T     = (sb_t*)alloc((size_t)1024*1024*2);
  sb_t* O3T     = (sb_t*)alloc((size_t)1024*1024*2);
  sb_t* S3T     = (sb_t*)alloc((size_t)1024*1024*2);
  sb_t* G3T     = (sb_t*)alloc((size_t)1024*1024*2);
  sb_t* s2Tall  = (sb_t*)alloc((size_t)4096*1024*2);  // [A2|O2|S2|G2] rows
  sb_t* O1T     = (sb_t*)alloc((size_t)1024*1024*2);
  sb_t* S1T     = (sb_t*)alloc((size_t)1024*1024*2);
  sb_t* A1T     = (sb_t*)alloc((size_t)1024*2048*2);
  sb_t* boxb    = (sb_t*)alloc((size_t)NB*12544*2);
  float* encP   = (float*)alloc((size_t)7*NB*EDIM*4);  // split-K partials (11 MB)
  sb_t* encMidb = (sb_t*)alloc((size_t)NB*EDIM*2);
  float* oB     = (float*)alloc((size_t)NB*EDIM*4);
  sb_t* oBb     = (sb_t*)alloc((size_t)NB*EDIM*2);
  float* hB     = (float*)alloc((size_t)NH*EDIM*4);
  sb_t* hBb     = (sb_t*)alloc((size_t)128*EDIM*2);
  sb_t* sp1b    = (sb_t*)alloc((size_t)PAIRS*128*2);
  sb_t* sp2b    = (sb_t*)alloc((size_t)PAIRS*256*2);
  sb_t* spFb    = (sb_t*)alloc((size_t)PAIRS*EDIM*2); // aliased as mbuf later
  sb_t* mbuf    = spFb;
  sb_t* s4      = (sb_t*)alloc((size_t)PAIRS*4096*2); // [sA|sO|sS|sG]
  float* ahA    = (float*)alloc((size_t)128*EDIM*4);
  float* aoA    = (float*)alloc((size_t)NB*EDIM*4);
  float* aoO    = (float*)alloc((size_t)NB*EDIM*4);
  float* ahS    = (float*)alloc((size_t)128*EDIM*4);
  float* aGv    = (float*)alloc((size_t)EDIM*4);
  float* adj    = (float*)alloc((size_t)PAIRS*4);
  float* wh     = (float*)alloc((size_t)PAIRS*4);
  float* wo     = (float*)alloc((size_t)PAIRS*4);
  sb_t* mwH     = (sb_t*)alloc((size_t)128*EDIM*2);
  sb_t* mwO     = (sb_t*)alloc((size_t)NB*EDIM*2);
  float* hmsg   = (float*)alloc((size_t)128*EDIM*4);
  float* omsg   = (float*)alloc((size_t)NB*EDIM*4);

  // ---- prep ----
  Prep17 pp;
  const int prepIdx[17] = {4,6,8,10,12,20,22,26,28,32,34,38,40,24,30,36,42};
  for (int i=0;i<17;++i) pp.p[i] = (const in_t*)d_in[prepIdx[i]];
  hipLaunchKernelGGL(prep_kernel, dim3(17), dim3(256), 0, stream, pp, pool);
  hipLaunchKernelGGL(gfeat_kernel, dim3(256), dim3(64), 0, stream, f3, pool + POOL_GFEAT);

  hipLaunchKernelGGL(tcvt_kernel, dim3(196,16), dim3(256), 0, stream, Wb1, Wb1T, 12544, 1024);
  hipLaunchKernelGGL(tcvt_kernel, dim3(16,16),  dim3(256), 0, stream, Wb2, Wb2T, 1024, 1024);
  hipLaunchKernelGGL(tcvt_kernel, dim3(2,4),    dim3(256), 0, stream, Ws2, Ws2T, 128, 256);
  hipLaunchKernelGGL(tcvt_kernel, dim3(4,16),   dim3(256), 0, stream, Ws3, Ws3T, 256, 1024);
  hipLaunchKernelGGL(tcvt_kernel, dim3(16,16),  dim3(256), 0, stream, A3, A3T, 1024, 1024);
  hipLaunchKernelGGL(tcvt_kernel, dim3(16,16),  dim3(256), 0, stream, O3, O3T, 1024, 1024);
  hipLaunchKernelGGL(tcvt_kernel, dim3(16,16),  dim3(256), 0, stream, S3, S3T, 1024, 1024);
  hipLaunchKernelGGL(tcvt_kernel, dim3(16,16),  dim3(256), 0, stream, G3, G3T, 1024, 1024);

  hipLaunchKernelGGL(pack_kt_kernel, dim3(16,16), dim3(256), 0, stream, A2, s2Tall,            1024);
  hipLaunchKernelGGL(pack_kt_kernel, dim3(16,16), dim3(256), 0, stream, O2, s2Tall+1024*1024,  1024);
  hipLaunchKernelGGL(pack_kt_kernel, dim3(16,16), dim3(256), 0, stream, S2, s2Tall+2048*1024,  1024);
  hipLaunchKernelGGL(pack_kt_kernel, dim3(16,16), dim3(256), 0, stream, G2, s2Tall+3072*1024,  1024);
  hipLaunchKernelGGL(pack_kt_kernel, dim3(16,16), dim3(256), 0, stream, O1, O1T, 1024);
  hipLaunchKernelGGL(pack_kt_kernel, dim3(16,16), dim3(256), 0, stream, S1, S1T, 1024);
  hipLaunchKernelGGL(pack_kt_kernel, dim3(32,16), dim3(256), 0, stream, A1, A1T, 2048);

  hipLaunchKernelGGL(cvt_kernel, dim3((NB*12544)/256), dim3(256), 0, stream, box, boxb, NB*12544);

  // ---- enc: split-K box GEMM (KS=1792, z=7) + combine, then @Wb2 (split-K) ----
  launch_mfma<2,0,float>(stream, NB, EDIM, 1792, 12544, 12544, 7,
      boxb, Wb1T, nullptr, encP, EDIM, 0, (long long)NB*EDIM, nullptr, nullptr, nullptr);
  hipLaunchKernelGGL((combineN_kernel<sb_t>), dim3(NB*EDIM/256), dim3(256), 0, stream,
                     encP, (long long)NB*EDIM, 7, pool+POOL_BB1, EDIM, 1, encMidb);
  launch_skinny(stream, NB, EDIM, EDIM, EDIM, EDIM, 4,
      encMidb, Wb2T, pool+POOL_BB2, oB, 1, encP);
  hipLaunchKernelGGL(encpost_kernel, dim3(NB,4), dim3(256), 0, stream, oB, oBb, hB, hBb);

  // ---- spatial MLP ----
  {
    dim3 g((PAIRS+63)/64, 2, 1);
    hipLaunchKernelGGL((gemm_valu<sb_t>), g, dim3(256), 0, stream,
        PAIRS, 128, SPA, spat, SPA, Ws1, 128, 0, pool+POOL_BS1, sp1b, 128, 1);
  }
  launch_mfma<0,1,sb_t>(stream, PAIRS, 256, 128, 128, 128, 1,
      sp1b, Ws2T, pool+POOL_BS2, sp2b, 256, 0, 0, nullptr, nullptr, nullptr);
  launch_mfma256<0,1,sb_t>(stream, PAIRS, EDIM, 256, 256, 256,
      sp2b, Ws3T, pool+POOL_BS3, spFb, EDIM, 0, nullptr, nullptr, nullptr);

  // ---- fused s-precompute: s4 = spF @ [A2|O2|S2|G2] + b2  (N=4096) ----
  launch_mfma256<0,0,sb_t>(stream, PAIRS, 4096, EDIM, EDIM, EDIM,
      spFb, s2Tall, pool+POOL_B2ALL, s4, 4096, 0, nullptr, nullptr, nullptr);

  // ---- aG = gfeat @ G1 + Gb1 (single row) ----
  {
    dim3 g(1, 1, 16);
    hipLaunchKernelGGL((gemm_valu<float>), g, dim3(256), 0, stream,
        1, 64, 256, pool+POOL_GFEAT, 256, G1, 64, 16384, pool+POOL_GB1, aGv, EDIM, 0);
  }

  // ---- 2 message-passing iterations ----
  for (int it=0; it<2; ++it) {
    // A-path -> adj
    launch_skinny(stream, 128, EDIM, EDIM, EDIM, 2048, 8,
        hBb, A1T, pool+POOL_AB1, ahA, 0, encP);
    launch_skinny(stream, NB, EDIM, EDIM, EDIM, 2048, 4,
        oBb, A1T+1024, nullptr, aoA, 0, encP);
    hipLaunchKernelGGL(mmake_kernel, dim3(PAIRS), dim3(256), 0, stream,
                       ahA, 1, 1024, aoA, 1, s4, 4096, 0, mbuf);
    (void)hipMemsetAsync(adj, 0, (size_t)PAIRS*4, stream);
    launch_mfma256<1,0,float>(stream, PAIRS, EDIM, EDIM, EDIM, EDIM,
        mbuf, A3T, nullptr, (float*)nullptr, 0, 0, Wadj, pool+POOL_AB3S, adj);
    hipLaunchKernelGGL(smax_h_kernel, dim3(NH), dim3(512), 0, stream, adj, wh);
    hipLaunchKernelGGL(smax_o_kernel, dim3(NB), dim3(64), 0, stream, adj, wo);

    // O-path -> h update
    launch_skinny(stream, NB, EDIM, EDIM, EDIM, 1024, 4,
        oBb, O1T, pool+POOL_OB1, aoO, 0, encP);
    hipLaunchKernelGGL(wredH_kernel, dim3(NH,8), dim3(128), 0, stream,
                       wh, aoO, s4, 1024, mwH);
    launch_skinny(stream, 128, EDIM, EDIM, EDIM, 1024, 8,
        mwH, O3T, nullptr, hmsg, 0, encP);
    hipLaunchKernelGGL(ln_update_kernel, dim3(NH), dim3(1024), 0, stream,
                       hmsg, pool+POOL_OB3S, gh, bh, hB, hBb);

    // S-path -> o update (uses updated h)
    launch_skinny(stream, 128, EDIM, EDIM, EDIM, 1024, 8,
        hBb, S1T, pool+POOL_SB1, ahS, 0, encP);
    hipLaunchKernelGGL(wredO_kernel, dim3(NB,8), dim3(128), 0, stream,
                       wo, ahS, s4, 2048, mwO);
    launch_skinny(stream, NB, EDIM, EDIM, EDIM, 1024, 4,
        mwO, S3T, nullptr, omsg, 0, encP);
    hipLaunchKernelGGL(ln_update_kernel, dim3(NB), dim3(1024), 0, stream,
                       omsg, pool+POOL_SB3S, go, bo, oB, oBb);
  }

  // ---- final heads ----
  launch_skinny(stream, 128, EDIM, EDIM, EDIM, 2048, 8,
      hBb, A1T, pool+POOL_AB1, ahA, 0, encP);
  launch_skinny(stream, NB, EDIM, EDIM, EDIM, 2048, 4,
      oBb, A1T+1024, nullptr, aoA, 0, encP);
  hipLaunchKernelGGL(mmake_kernel, dim3(PAIRS), dim3(256), 0, stream,
                     ahA, 1, 1024, aoA, 1, s4, 4096, 0, mbuf);
  launch_mfma256<0,1,out_t>(stream, PAIRS, EDIM, EDIM, EDIM, EDIM,
      mbuf, A3T, pool+POOL_AB3S, out, 2048, 0, nullptr, nullptr, nullptr);

  hipLaunchKernelGGL(mmake_kernel, dim3(PAIRS), dim3(256), 0, stream,
                     aGv, 1, 0, nullptr, 0, s4, 4096, 3072, mbuf);
  launch_mfma256<0,1,out_t>(stream, PAIRS, EDIM, EDIM, EDIM, EDIM,
      mbuf, G3T, pool+POOL_GB3S, out, 2048, 1024, nullptr, nullptr, nullptr);
}

// Round 8
// 1446.994 us; speedup vs baseline: 1.0245x; 1.0047x over previous
//
#include <hip/hip_runtime.h>
#include <hip/hip_bf16.h>
#include <cstdint>
#include <cstddef>

// ---------------- problem constants ----------------
#define NH    64
#define NB    384
#define EDIM  1024
#define PAIRS (NH*NB)   // 24576
#define SPA   36

using in_t  = float;
using out_t = float;
using sb_t  = __hip_bfloat16;

typedef short bf16x8 __attribute__((ext_vector_type(8)));
typedef float f32x4  __attribute__((ext_vector_type(4)));

static __device__ __forceinline__ float cvt(float x){ return x; }
static __device__ __forceinline__ float cvt(__hip_bfloat16 x){ return __bfloat162float(x); }
static __device__ __forceinline__ void stv(float* p, float v){ *p = v; }
static __device__ __forceinline__ void stv(__hip_bfloat16* p, float v){ *p = __float2bfloat16(v); }

static __device__ __forceinline__ float b2f(unsigned short u){
  union { unsigned int i; float f; } x; x.i = ((unsigned int)u)<<16; return x.f;
}

typedef const __attribute__((address_space(1))) void* as1_t;
typedef __attribute__((address_space(3))) void* as3_t;
static __device__ __forceinline__ void gl_lds16(const void* g, void* l){
  __builtin_amdgcn_global_load_lds((as1_t)g, (as3_t)l, 16, 0, 0);
}

// ---------------- bias/constant pool layout (floats) ----------------
#define POOL_BB1   0
#define POOL_BB2   1024
#define POOL_BS1   2048
#define POOL_BS2   2176
#define POOL_BS3   2432
#define POOL_AB1   3456
#define POOL_GB1   4480
#define POOL_SB1   5504
#define POOL_OB1   6528
#define POOL_B2ALL 7552          // 4096: [AB2|OB2|SB2|GB2]
#define POOL_AB3S  11648
#define POOL_GB3S  12672
#define POOL_SB3S  13696
#define POOL_OB3S  14720
#define POOL_GFEAT 15744
#define POOL_TOTAL 16000

// ============================================================================
// MFMA bf16 GEMM, 128x128 tile, BK=64 (two 32-wide sub-tiles), 4 waves.
// (kept for small/odd shapes; EPI2 = split-K partial writer)
// ============================================================================
template<int EPI, int RELU, typename TC>
__global__ __launch_bounds__(256)
void gemm_mfma(int M, int N, int KS, int lda, int ldb,
               const sb_t* __restrict__ A,
               const sb_t* __restrict__ Bt,
               const float* __restrict__ bias,
               TC* __restrict__ C, int ldc, int coff, long long strideCz,
               const float* __restrict__ Wadj,
               const float* __restrict__ ab3s,
               float* __restrict__ adjOut)
{
  __shared__ alignas(16) short lA[2][128*32];
  __shared__ alignas(16) short lB[2][128*32];
  const int tid = threadIdx.x;
  const int w = tid >> 6, l = tid & 63;
  const int m0 = blockIdx.x * 128, n0 = blockIdx.y * 128;
  const int wr = w >> 1, wc = w & 1;
  const int Koff = blockIdx.z * KS;

  const int srow = w*32 + (l>>2);
  const int scol = (l&3)*8;
  const sb_t* gA = A  + (size_t)(m0 + srow)*(size_t)lda + Koff + scol;
  const sb_t* gB = Bt + (size_t)(n0 + srow)*(size_t)ldb + Koff + scol;
  short* lA0 = &lA[0][(w*32)*32];
  short* lA1 = &lA[1][(w*32)*32];
  short* lB0 = &lB[0][(w*32)*32];
  short* lB1 = &lB[1][(w*32)*32];

  f32x4 acc[4][4];
  const f32x4 zz = {0.f,0.f,0.f,0.f};
  #pragma unroll
  for (int i=0;i<4;++i)
    #pragma unroll
    for (int j=0;j<4;++j) acc[i][j] = zz;

  const int fr  = l & 15;
  const int fko = (l >> 4) * 8;

  for (int k0 = 0; k0 < KS; k0 += 64) {
    gl_lds16(gA + k0,               lA0);
    gl_lds16(gA + k0 + 16*lda,      lA0 + 16*32);
    gl_lds16(gA + k0 + 32,          lA1);
    gl_lds16(gA + k0 + 32 + 16*lda, lA1 + 16*32);
    gl_lds16(gB + k0,               lB0);
    gl_lds16(gB + k0 + 16*ldb,      lB0 + 16*32);
    gl_lds16(gB + k0 + 32,          lB1);
    gl_lds16(gB + k0 + 32 + 16*ldb, lB1 + 16*32);
    __syncthreads();
    #pragma unroll
    for (int kh=0; kh<2; ++kh) {
      bf16x8 af[4], bfv[4];
      #pragma unroll
      for (int i=0;i<4;++i)
        af[i]  = *(const bf16x8*)&lA[kh][(wr*64 + i*16 + fr)*32 + fko];
      #pragma unroll
      for (int j=0;j<4;++j)
        bfv[j] = *(const bf16x8*)&lB[kh][(wc*64 + j*16 + fr)*32 + fko];
      #pragma unroll
      for (int i=0;i<4;++i)
        #pragma unroll
        for (int j=0;j<4;++j)
          acc[i][j] = __builtin_amdgcn_mfma_f32_16x16x32_bf16(af[i], bfv[j], acc[i][j], 0, 0, 0);
    }
    __syncthreads();
  }

  const int cn = l & 15;
  const int cr = (l >> 4) * 4;

  if (EPI == 1) {
    float part[4][4];
    #pragma unroll
    for (int i=0;i<4;++i)
      #pragma unroll
      for (int r=0;r<4;++r) part[i][r] = 0.f;
    #pragma unroll
    for (int j=0;j<4;++j) {
      const int col = n0 + wc*64 + j*16 + cn;
      const float wv = Wadj[col];
      const float bv = ab3s[col];
      #pragma unroll
      for (int i=0;i<4;++i)
        #pragma unroll
        for (int r=0;r<4;++r)
          part[i][r] += fmaxf(acc[i][j][r] + bv, 0.f) * wv;
    }
    #pragma unroll
    for (int m=1;m<16;m<<=1)
      #pragma unroll
      for (int i=0;i<4;++i)
        #pragma unroll
        for (int r=0;r<4;++r)
          part[i][r] += __shfl_xor(part[i][r], m, 64);
    if (cn == 0) {
      #pragma unroll
      for (int i=0;i<4;++i)
        #pragma unroll
        for (int r=0;r<4;++r)
          atomicAdd(&adjOut[m0 + wr*64 + i*16 + cr + r], part[i][r]);
    }
    return;
  }

  #pragma unroll
  for (int j=0;j<4;++j) {
    const int col = n0 + wc*64 + j*16 + cn;
    const float bv = (EPI==0 && bias) ? bias[col] : 0.f;
    #pragma unroll
    for (int i=0;i<4;++i) {
      #pragma unroll
      for (int r=0;r<4;++r) {
        const int row = m0 + wr*64 + i*16 + cr + r;
        float v = acc[i][j][r] + bv;
        if (RELU) v = fmaxf(v, 0.f);
        if (EPI == 2)
          stv(&C[(size_t)blockIdx.z*strideCz + (size_t)row*ldc + col], v);
        else
          stv(&C[(size_t)row*ldc + coff + col], v);
      }
    }
  }
}

// ============================================================================
// 256x256 MFMA GEMM, 16x16x32 MFMA, TWO merged phases per K-tile (r8):
// 32 MFMA + 8-16 ds_reads per phase, ONE barrier per phase (2/K-tile).
// Hazard audit (drift window = one merged phase):
//  P12 stages S3(t+1) -> buf[pn]; that region (A rows {64-127,192-255}) was
//    read by tile t-1's P34 (same parity buffer), drained before its
//    phase-end barrier; S3 issued after it. OK.
//  P34 stages S0,S1(t+2) (B rows of buf[cur], read wholly in P12, drained
//    before P12-end barrier) and S2(t+2) (A rows {0-63,128-191} = sub-phases
//    0-1, read in P12, drained). OK.
//  vmcnt trace: per tile 8 gl_lds issues (2 in P12, 6 in P34); steady-state
//    P34 vmcnt(6) drains exactly S0..S3(t+1). Same cadence as 4-phase r7.
// T1 XCD-swizzle, T2 LDS XOR-swizzle (chunk ^= row&7), T3/T4 counted vmcnt(6),
// T5 setprio. C = A[M,K] @ Bt[N,K]^T ; M%256==0, N%256==0, K%64==0, K>=128.
// Epilogue: C staged through 128 KiB LDS (chunk-XOR swizzled) + nontemporal
// 16B coalesced global stores.
// ============================================================================
template<int EPI, int RELU, typename TC>
__global__ __launch_bounds__(512, 2)
void gemm256(int M, int N, int K, int lda, int ldb,
             const sb_t* __restrict__ A,
             const sb_t* __restrict__ Bt,
             const float* __restrict__ bias,
             TC* __restrict__ C, int ldc, int coff,
             const float* __restrict__ Wadj,
             const float* __restrict__ ab3s,
             float* __restrict__ adjOut)
{
  __shared__ alignas(16) short sh[2][2][256*64];   // [buf][0=A,1=B], 128 KiB

  const int tid = threadIdx.x;
  const int w = tid >> 6, l = tid & 63;
  const int wr = w >> 2, wc = w & 3;

  // T1: XCD-chunked bijective swizzle, y-fastest within chunk.
  const unsigned gx = gridDim.x, gy = gridDim.y;
  const unsigned nwg = gx * gy;
  const unsigned hwid = blockIdx.x + gx * blockIdx.y;
  const unsigned q = nwg >> 3, rr = nwg & 7;
  const unsigned xcd = hwid & 7, jj = hwid >> 3;
  const unsigned wg = (xcd < rr ? xcd*(q+1) : rr*(q+1) + (xcd-rr)*q) + jj;
  const int by = (int)(wg % gy), bx = (int)(wg / gy);
  const int m0 = bx * 256, n0 = by * 256;

  const int NT = K >> 6;

  // staging: lane l covers row (l>>3), dest chunk (l&7); source pre-swizzled.
  const int lr = l >> 3;
  const int lch = ((l & 7) ^ lr) * 8;

  auto stage = [&](int p, int s, int t){
    short* lbA = &sh[p][0][0];
    short* lbB = &sh[p][1][0];
    const int k0 = t * 64;
    #pragma unroll
    for (int c=0;c<2;++c){
      const int g = (w<<1) + c;          // 0..15, wave-uniform
      int row0; const sb_t* mat; int ld; int rb; short* dst;
      if (s==0){ row0 = g*8;                              mat=Bt; ld=ldb; rb=n0; dst=lbB; }
      else if (s==1){ row0 = 128 + g*8;                   mat=Bt; ld=ldb; rb=n0; dst=lbB; }
      else if (s==2){ row0 = (g<8)? g*8    : 128+(g-8)*8; mat=A;  ld=lda; rb=m0; dst=lbA; }
      else          { row0 = (g<8)? 64+g*8 : 192+(g-8)*8; mat=A;  ld=lda; rb=m0; dst=lbA; }
      gl_lds16(mat + (size_t)(rb + row0 + lr)*(size_t)ld + k0 + lch, dst + row0*64);
    }
  };

  // fragment-read per-lane constants (16x16x32 layout)
  const int fr = l & 15;
  const int fg = l >> 4;
  const int sx = fr & 7;
  const int x0 = ((0 + fg) ^ sx) * 8;    // kk=0 swizzled chunk (shorts)
  const int x1 = ((4 + fg) ^ sx) * 8;    // kk=1
  const int oA = (wr*128 + fr) * 64;
  const int oB = (wc*64  + fr) * 64;

  f32x4 acc[8][4];
  const f32x4 zz = {0.f,0.f,0.f,0.f};
  #pragma unroll
  for (int i=0;i<8;++i)
    #pragma unroll
    for (int j=0;j<4;++j) acc[i][j] = zz;

#define G256_BAR()   __builtin_amdgcn_s_barrier()
#define G256_LGKM(n) asm volatile("s_waitcnt lgkmcnt(" #n ")" ::: "memory")
#define G256_VM(n)   asm volatile("s_waitcnt vmcnt(" #n ")" ::: "memory")
#define G256_LOADA(b)                                                    \
  _Pragma("unroll") for (int ii=0; ii<4; ++ii){                          \
    af[ii][0] = *(const bf16x8*)(sa + oA + (4*(b)+ii)*1024 + x0);        \
    af[ii][1] = *(const bf16x8*)(sa + oA + (4*(b)+ii)*1024 + x1);        \
  }
#define G256_MFMA(b)                                                    \
  do { __builtin_amdgcn_s_setprio(1);                                    \
    _Pragma("unroll") for (int kk=0; kk<2; ++kk)                         \
    _Pragma("unroll") for (int ii=0; ii<4; ++ii)                         \
    _Pragma("unroll") for (int j=0; j<4; ++j)                            \
      acc[4*(b)+ii][j] = __builtin_amdgcn_mfma_f32_16x16x32_bf16(        \
          af[ii][kk], bf[j][kk], acc[4*(b)+ii][j], 0, 0, 0);             \
    __builtin_amdgcn_s_setprio(0); } while(0)

  // ---- prologue: tile0 S0..S3, vm(4), tile1 S0..S2, vm(6) ----
  stage(0,0,0); stage(0,1,0); stage(0,2,0); stage(0,3,0);
  G256_VM(4);
  if (NT > 1) {
    stage(1,0,1); stage(1,1,1); stage(1,2,1);
    G256_VM(6);
  } else {
    G256_VM(0);
  }
  G256_BAR();

  for (int t=0; t<NT; ++t) {
    const int cur = t & 1, pn = cur ^ 1;
    short* sa  = &sh[cur][0][0];
    short* sb2 = &sh[cur][1][0];
    bf16x8 bf[4][2], af[4][2];

    // ---- merged P12: read B(8)+A0..A1(8), stage S3(t+1), 32 MFMA, bar ----
    #pragma unroll
    for (int j=0;j<4;++j){
      bf[j][0] = *(const bf16x8*)(sb2 + oB + j*1024 + x0);
      bf[j][1] = *(const bf16x8*)(sb2 + oB + j*1024 + x1);
    }
    G256_LOADA(0);
    if (t+1 < NT) stage(pn, 3, t+1);
    G256_LGKM(0);
    G256_MFMA(0);
    G256_BAR();

    // ---- merged P34: read A2..A3(8), stage S0,S1,S2(t+2), 32 MFMA ----
    G256_LOADA(1);
    if (t+2 < NT){ stage(cur, 0, t+2); stage(cur, 1, t+2); stage(cur, 2, t+2); }
    G256_LGKM(0);
    G256_MFMA(1);
    if (t+1 < NT) {
      if (t+2 < NT) { G256_VM(6); } else { G256_VM(0); }
    }
    G256_BAR();
  }

#undef G256_LOADA
#undef G256_MFMA

  // ---- epilogue ----
  const int cn = l & 15;
  const int cr = (l >> 4) * 4;

  if (EPI == 1) {
    float part[8][4];
    #pragma unroll
    for (int i=0;i<8;++i)
      #pragma unroll
      for (int r=0;r<4;++r) part[i][r] = 0.f;
    #pragma unroll
    for (int j=0;j<4;++j) {
      const int col = n0 + wc*64 + j*16 + cn;
      const float wv = Wadj[col];
      const float bv = ab3s[col];
      #pragma unroll
      for (int i=0;i<8;++i)
        #pragma unroll
        for (int r=0;r<4;++r)
          part[i][r] += fmaxf(acc[i][j][r] + bv, 0.f) * wv;
    }
    #pragma unroll
    for (int m=1;m<16;m<<=1)
      #pragma unroll
      for (int i=0;i<8;++i)
        #pragma unroll
        for (int r=0;r<4;++r)
          part[i][r] += __shfl_xor(part[i][r], m, 64);
    if (cn == 0) {
      #pragma unroll
      for (int i=0;i<8;++i)
        #pragma unroll
        for (int r=0;r<4;++r)
          atomicAdd(&adjOut[m0 + wr*128 + i*16 + cr + r], part[i][r]);
    }
    return;
  }

  // EPI0: LDS-staged coalesced C store (chunk-XOR swizzled, nontemporal)
  if constexpr (sizeof(TC) == 2) {
    sb_t* ebs = (sb_t*)&sh[0][0][0];     // 256x256 bf16 = 128 KiB
    G256_LGKM(0);
    G256_BAR();
    #pragma unroll
    for (int i=0;i<8;++i){
      #pragma unroll
      for (int j=0;j<4;++j){
        const int lcol = wc*64 + j*16 + cn;
        const float bv = bias ? bias[n0 + lcol] : 0.f;
        const int cb = lcol >> 3, ce = lcol & 7;
        #pragma unroll
        for (int r=0;r<4;++r){
          const int lrow = wr*128 + i*16 + cr + r;
          float v = acc[i][j][r] + bv;
          if (RELU) v = fmaxf(v, 0.f);
          stv(&ebs[lrow*256 + ((cb ^ (lrow & 7)) << 3) + ce], v);
        }
      }
    }
    G256_LGKM(0);
    G256_BAR();
    #pragma unroll
    for (int p=0;p<16;++p){
      const int R = p*16 + (tid>>5);
      const int c = tid & 31;
      bf16x8 v = *(const bf16x8*)((const short*)ebs + R*256 + ((c ^ (R & 7)) << 3));
      __builtin_nontemporal_store(v,
          (bf16x8*)((short*)C + (size_t)(m0+R)*ldc + coff + n0 + c*8));
    }
  } else {
    // f32: two 128-row passes
    float* ebf = (float*)&sh[0][0][0];   // 128x256 f32 = 128 KiB
    #pragma unroll
    for (int h=0; h<2; ++h){
      G256_LGKM(0);
      G256_BAR();
      if (wr == h){
        #pragma unroll
        for (int i=0;i<8;++i){
          #pragma unroll
          for (int j=0;j<4;++j){
            const int lcol = wc*64 + j*16 + cn;
            const float bv = bias ? bias[n0 + lcol] : 0.f;
            const int cb = lcol >> 2, ce = lcol & 3;
            #pragma unroll
            for (int r=0;r<4;++r){
              const int lrow = i*16 + cr + r;
              float v = acc[i][j][r] + bv;
              if (RELU) v = fmaxf(v, 0.f);
              ebf[lrow*256 + ((cb ^ (lrow & 7)) << 2) + ce] = v;
            }
          }
        }
      }
      G256_LGKM(0);
      G256_BAR();
      #pragma unroll
      for (int p=0;p<16;++p){
        const int R = p*8 + (tid>>6);
        const int c = tid & 63;
        f32x4 v = *(const f32x4*)&ebf[R*256 + ((c ^ (R & 7)) << 2)];
        __builtin_nontemporal_store(v,
            (f32x4*)((float*)C + (size_t)(m0 + h*128 + R)*ldc + coff + n0 + c*4));
      }
    }
  }
#undef G256_BAR
#undef G256_LGKM
#undef G256_VM
}

// ============================================================================
// fp32 VALU GEMM (tiny/odd shapes: spatial 36->128, gfeat@G1)
// ============================================================================
template<typename TC>
__global__ __launch_bounds__(256)
void gemm_valu(int M, int N, int K,
               const in_t* __restrict__ S, int ldsS,
               const in_t* __restrict__ B, int ldb, long long strideB,
               const float* __restrict__ bias,
               TC* __restrict__ C, int ldc, int reluOut)
{
  __shared__ float As[16][65];
  __shared__ float Bs[16][68];
  const int z  = blockIdx.z;
  const in_t* Bz = B + (long long)z * strideB;
  const int m0 = blockIdx.x * 64;
  const int n0 = blockIdx.y * 64;
  const int tid = threadIdx.x;
  const int tx = tid & 15;
  const int ty = tid >> 4;

  float acc[4][4];
  #pragma unroll
  for (int i=0;i<4;++i)
    #pragma unroll
    for (int j=0;j<4;++j) acc[i][j]=0.f;

  const int kTiles = (K + 15) >> 4;
  for (int kt=0; kt<kTiles; ++kt) {
    const int k0 = kt << 4;
    #pragma unroll
    for (int q=0;q<4;++q) {
      const int p = m0 + ty + 16*q;
      const int c = k0 + tx;
      As[tx][ty+16*q] = (p < M && c < K) ? S[(size_t)p*ldsS + c] : 0.f;
    }
    {
      const int n = tid & 63;
      #pragma unroll
      for (int q=0;q<4;++q) {
        const int kk = (tid >> 6) + 4*q;
        const int gk = k0 + kk;
        const int gn = n0 + n;
        Bs[kk][n] = (gk < K && gn < N) ? Bz[(size_t)gk*ldb + gn] : 0.f;
      }
    }
    __syncthreads();
    #pragma unroll
    for (int kk=0; kk<16; ++kk) {
      float a[4], b[4];
      #pragma unroll
      for (int i=0;i<4;++i) a[i] = As[kk][ty + 16*i];
      #pragma unroll
      for (int j=0;j<4;++j) b[j] = Bs[kk][tx + 16*j];
      #pragma unroll
      for (int i=0;i<4;++i)
        #pragma unroll
        for (int j=0;j<4;++j) acc[i][j] += a[i]*b[j];
    }
    __syncthreads();
  }
  #pragma unroll
  for (int i=0;i<4;++i) {
    const int r = m0 + ty + 16*i;
    if (r >= M) continue;
    #pragma unroll
    for (int j=0;j<4;++j) {
      const int nn = n0 + tx + 16*j;
      if (nn >= N) continue;
      const int ccol = z*N + nn;
      float v = acc[i][j];
      if (bias) v += bias[ccol];
      if (reluOut) v = fmaxf(v, 0.f);
      stv(&C[(size_t)r*ldc + ccol], v);
    }
  }
}

// ============================================================================
// prep kernels
// ============================================================================
struct Prep17 { const in_t* p[17]; };

__global__ __launch_bounds__(256)
void prep_kernel(Prep17 a, float* __restrict__ pool)
{
  const int len[17] = {1024,1024,128,256,1024,1024,1024,1024,1024,1024,1024,1024,1024,
                       1024,1024,1024,1024};
  const int off[17] = {POOL_BB1,POOL_BB2,POOL_BS1,POOL_BS2,POOL_BS3,POOL_AB1,
                       POOL_B2ALL+0,      // AB2
                       POOL_GB1,
                       POOL_B2ALL+3072,   // GB2
                       POOL_SB1,
                       POOL_B2ALL+2048,   // SB2
                       POOL_OB1,
                       POOL_B2ALL+1024,   // OB2
                       POOL_AB3S,POOL_GB3S,POOL_SB3S,POOL_OB3S};
  const int j = blockIdx.x;
  const in_t* src = a.p[j];
  const int L = len[j], o = off[j];
  for (int i = threadIdx.x; i < L; i += blockDim.x) {
    if (j < 13) {
      pool[o+i] = src[i];
    } else {
      float s = 0.f;
      for (int k=0;k<16;++k) s += src[k*1024 + i];
      pool[o+i] = s;
    }
  }
}

__global__ __launch_bounds__(64)
void gfeat_kernel(const in_t* __restrict__ f3, float* __restrict__ g)
{
  const int c = blockIdx.x;
  const int t = threadIdx.x;
  float s = (t < 49) ? f3[c*49 + t] : 0.f;
  #pragma unroll
  for (int o=32;o>0;o>>=1) s += __shfl_down(s, o, 64);
  if (t == 0) g[c] = s * (1.0f/49.0f);
}

// f32 (R x C) -> bf16 (C x R)
__global__ __launch_bounds__(256)
void tcvt_kernel(const float* __restrict__ in, sb_t* __restrict__ outT, int R, int C)
{
  __shared__ float t[64][65];
  const int r0 = blockIdx.x*64, c0 = blockIdx.y*64;
  const int x = threadIdx.x & 63, y = threadIdx.x >> 6;
  #pragma unroll 4
  for (int q=0;q<16;++q){ const int rl = q*4 + y; t[rl][x] = in[(size_t)(r0+rl)*C + c0 + x]; }
  __syncthreads();
  #pragma unroll 4
  for (int q=0;q<16;++q){ const int cl = q*4 + y; stv(&outT[(size_t)(c0+cl)*R + r0 + x], t[x][cl]); }
}

// W (16, Cdim, 64) f32 -> PT[k*64+u][c] bf16
__global__ __launch_bounds__(256)
void pack_kt_kernel(const float* __restrict__ W, sb_t* __restrict__ PT, int Cdim)
{
  __shared__ float t[64][65];
  const int c0 = blockIdx.x*64; const int k = blockIdx.y;
  const int x = threadIdx.x & 63, y = threadIdx.x >> 6;
  #pragma unroll 4
  for (int q=0;q<16;++q){ const int cl = q*4 + y; t[cl][x] = W[((size_t)k*Cdim + c0 + cl)*64 + x]; }
  __syncthreads();
  #pragma unroll 4
  for (int q=0;q<16;++q){ const int u = q*4 + y; stv(&PT[((size_t)k*64 + u)*Cdim + c0 + x], t[x][u]); }
}

__global__ void cvt_kernel(const float* __restrict__ in, sb_t* __restrict__ o, int n){
  const int i = blockIdx.x*256 + threadIdx.x;
  if (i < n) stv(&o[i], in[i]);
}

// generic split-K combine: out[i] = (relu?)( sum_z part[z*stride+i] + bias[i&(N-1)] )
template<typename TO>
__global__ __launch_bounds__(256)
void combineN_kernel(const float* __restrict__ part, long long stride, int nz,
                     const float* __restrict__ bias, int N, int relu,
                     TO* __restrict__ out)
{
  const int i = blockIdx.x*256 + threadIdx.x;
  float v = bias ? bias[i & (N-1)] : 0.f;
  for (int z=0; z<nz; ++z) v += part[(long long)z*stride + i];
  if (relu) v = fmaxf(v, 0.f);
  stv(&out[i], v);
}

// enc fp32 -> bf16 mirror + h fp32/bf16 copies
__global__ __launch_bounds__(256)
void encpost_kernel(const float* __restrict__ oB, sb_t* __restrict__ oBb,
                    float* __restrict__ hB, sb_t* __restrict__ hBb)
{
  const int p = blockIdx.x; const int c = blockIdx.y*256 + threadIdx.x;
  const float v = oB[(size_t)p*1024 + c];
  stv(&oBb[(size_t)p*1024+c], v);
  if (p < NH){ hB[(size_t)p*1024+c] = v; stv(&hBb[(size_t)p*1024+c], v); }
}

// m[p,c] = bf16( relu( (U[p/NB,c] + V[p%NB,c]) * S4[p, colOff+c] ) )
__global__ __launch_bounds__(256)
void mmake_kernel(const float* __restrict__ U, int hasU, int ldu,
                  const float* __restrict__ V, int hasV,
                  const sb_t* __restrict__ S, int ldS, int colOff,
                  sb_t* __restrict__ Mo)
{
  const int p = blockIdx.x;
  const int c = threadIdx.x * 4;
  const ushort4 sv = *(const ushort4*)((const unsigned short*)S + (size_t)p*ldS + colOff + c);
  float a0=0.f,a1=0.f,a2=0.f,a3=0.f;
  if (hasU){ const float* Up = U + (size_t)(p/NB)*ldu + c; a0=Up[0];a1=Up[1];a2=Up[2];a3=Up[3]; }
  if (hasV){ const float* Vp = V + (size_t)(p%NB)*1024 + c; a0+=Vp[0];a1+=Vp[1];a2+=Vp[2];a3+=Vp[3]; }
  __hip_bfloat16* mo = (__hip_bfloat16*)Mo + (size_t)p*1024 + c;
  mo[0] = __float2bfloat16(fmaxf(a0*b2f(sv.x),0.f));
  mo[1] = __float2bfloat16(fmaxf(a1*b2f(sv.y),0.f));
  mo[2] = __float2bfloat16(fmaxf(a2*b2f(sv.z),0.f));
  mo[3] = __float2bfloat16(fmaxf(a3*b2f(sv.w),0.f));
}

// softmax over n of adj[hh,:] -> wh[hh,n]
__global__ __launch_bounds__(512)
void smax_h_kernel(const float* __restrict__ adj, float* __restrict__ wh)
{
  __shared__ float red[512];
  const int hh = blockIdx.x, t = threadIdx.x;
  float av = (t < NB) ? adj[hh*NB + t] : -1e30f;
  red[t]=av; __syncthreads();
  for (int s=256;s>0;s>>=1){ if(t<s) red[t]=fmaxf(red[t],red[t+s]); __syncthreads(); }
  float mx = red[0]; __syncthreads();
  float e = (t < NB) ? __expf(av - mx) : 0.f;
  red[t]=e; __syncthreads();
  for (int s=256;s>0;s>>=1){ if(t<s) red[t]+=red[t+s]; __syncthreads(); }
  if (t < NB) wh[hh*NB + t] = e / red[0];
}

// softmax over h of adj[:,n] -> wo[n,h]
__global__ __launch_bounds__(64)
void smax_o_kernel(const float* __restrict__ adj, float* __restrict__ wo)
{
  const int n = blockIdx.x, t = threadIdx.x;
  float av = adj[t*NB + n];
  float mx = av;
  #pragma unroll
  for (int o=32;o>0;o>>=1) mx = fmaxf(mx, __shfl_xor(mx, o, 64));
  float e = __expf(av - mx);
  float s = e;
  #pragma unroll
  for (int o=32;o>0;o>>=1) s += __shfl_xor(s, o, 64);
  wo[n*64 + t] = e / s;
}

// mw_h[hh,c] = sum_n wh[hh,n]*relu(aoO[n,c]*sO[hh*NB+n, c])
__global__ __launch_bounds__(128)
void wredH_kernel(const float* __restrict__ wh, const float* __restrict__ ao,
                  const sb_t* __restrict__ s4, int colOff, sb_t* __restrict__ mw)
{
  const int hh = blockIdx.x;
  const int c = blockIdx.y*128 + threadIdx.x;
  const unsigned short* sp = (const unsigned short*)s4 + (size_t)hh*NB*4096 + colOff + c;
  const float* whp = wh + hh*NB;
  float acc = 0.f;
  for (int n=0; n<NB; ++n)
    acc += whp[n] * fmaxf(ao[(size_t)n*1024 + c] * b2f(sp[(size_t)n*4096]), 0.f);
  stv(&mw[(size_t)hh*1024 + c], acc);
}

// mw_o[n,c] = sum_h wo[n,h]*relu(ahS[h,c]*sH[h*NB+n, c])
__global__ __launch_bounds__(128)
void wredO_kernel(const float* __restrict__ wo, const float* __restrict__ ah,
                  const sb_t* __restrict__ s4, int colOff, sb_t* __restrict__ mw)
{
  const int n = blockIdx.x;
  const int c = blockIdx.y*128 + threadIdx.x;
  const unsigned short* sp = (const unsigned short*)s4 + (size_t)n*4096 + colOff + c;
  const float* wop = wo + n*64;
  float acc = 0.f;
  for (int h=0; h<NH; ++h)
    acc += wop[h] * fmaxf(ah[(size_t)h*1024 + c] * b2f(sp[(size_t)h*NB*4096]), 0.f);
  stv(&mw[(size_t)n*1024 + c], acc);
}

static __device__ __forceinline__ float bsum(float v, float* red){
  const int t = threadIdx.x;
  red[t]=v; __syncthreads();
  for (int s=512;s>0;s>>=1){ if(t<s) red[t]+=red[t+s]; __syncthreads(); }
  float r = red[0]; __syncthreads();
  return r;
}

// x[row,:] = LN( x + relu(msg[row,:] + b3s) ) * g + b ; also bf16 mirror
__global__ __launch_bounds__(1024)
void ln_update_kernel(const float* __restrict__ msg, const float* __restrict__ b3s,
                      const in_t* __restrict__ g, const in_t* __restrict__ b,
                      float* __restrict__ x, sb_t* __restrict__ xb)
{
  __shared__ float red[1024];
  const int row = blockIdx.x, t = threadIdx.x;
  float val = x[(size_t)row*1024 + t] + fmaxf(msg[(size_t)row*1024 + t] + b3s[t], 0.f);
  float mean = bsum(val, red) * (1.0f/1024.0f);
  float d = val - mean;
  float var = bsum(d*d, red) * (1.0f/1024.0f);
  float y = d * rsqrtf(var + 1e-5f) * g[t] + b[t];
  x[(size_t)row*1024 + t] = y;
  stv(&xb[(size_t)row*1024 + t], y);
}

// ---------------- host-side launchers ----------------
template<int EPI, int RELU, typename TC>
static inline void launch_mfma(hipStream_t st, int M, int N, int KS, int lda, int ldb, int nz,
    const sb_t* A, const sb_t* Bt, const float* bias, TC* C, int ldc, int coff,
    long long strideCz, const float* Wadj, const float* ab3s, float* adjOut)
{
  dim3 g((unsigned)(M/128), (unsigned)(N/128), (unsigned)nz);
  hipLaunchKernelGGL((gemm_mfma<EPI,RELU,TC>), g, dim3(256), 0, st,
                     M,N,KS,lda,ldb,A,Bt,bias,C,ldc,coff,strideCz,Wadj,ab3s,adjOut);
}

template<int EPI, int RELU, typename TC>
static inline void launch_mfma256(hipStream_t st, int M, int N, int K, int lda, int ldb,
    const sb_t* A, const sb_t* Bt, const float* bias, TC* C, int ldc, int coff,
    const float* Wadj, const float* ab3s, float* adjOut)
{
  dim3 g((unsigned)(M/256), (unsigned)(N/256), 1);
  hipLaunchKernelGGL((gemm256<EPI,RELU,TC>), g, dim3(512), 0, st,
                     M,N,K,lda,ldb,A,Bt,bias,C,ldc,coff,Wadj,ab3s,adjOut);
}

// split-K skinny GEMM: partials via EPI2 into scratch, then combineN -> f32 out
static inline void launch_skinny(hipStream_t st, int M, int N, int K, int lda, int ldb, int nz,
    const sb_t* A, const sb_t* Bt, const float* bias, float* outp, int relu, float* scratch)
{
  launch_mfma<2,0,float>(st, M, N, K/nz, lda, ldb, nz, A, Bt, nullptr, scratch, N, 0,
                         (long long)M*N, nullptr, nullptr, nullptr);
  hipLaunchKernelGGL((combineN_kernel<float>), dim3((unsigned)((M*N)/256)), dim3(256), 0, st,
                     scratch, (long long)M*N, nz, bias, N, relu, outp);
}

extern "C" void kernel_launch(void* const* d_in, const int* in_sizes, int n_in,
                              void* d_out, int out_size, void* d_ws, size_t ws_size,
                              hipStream_t stream)
{
  (void)in_sizes; (void)n_in; (void)out_size; (void)ws_size;

  const in_t* box  = (const in_t*)d_in[0];
  const in_t* spat = (const in_t*)d_in[1];
  const in_t* f3   = (const in_t*)d_in[2];
  const in_t* Wb1  = (const in_t*)d_in[3];
  const in_t* Wb2  = (const in_t*)d_in[5];
  const in_t* Ws1  = (const in_t*)d_in[7];
  const in_t* Ws2  = (const in_t*)d_in[9];
  const in_t* Ws3  = (const in_t*)d_in[11];
  const in_t* Wadj = (const in_t*)d_in[13];
  const in_t* gh   = (const in_t*)d_in[15];
  const in_t* bh   = (const in_t*)d_in[16];
  const in_t* go   = (const in_t*)d_in[17];
  const in_t* bo   = (const in_t*)d_in[18];
  const in_t* A1   = (const in_t*)d_in[19];
  const in_t* A2   = (const in_t*)d_in[21];
  const in_t* A3   = (const in_t*)d_in[23];
  const in_t* G1   = (const in_t*)d_in[25];
  const in_t* G2   = (const in_t*)d_in[27];
  const in_t* G3   = (const in_t*)d_in[29];
  const in_t* S1   = (const in_t*)d_in[31];
  const in_t* S2   = (const in_t*)d_in[33];
  const in_t* S3   = (const in_t*)d_in[35];
  const in_t* O1   = (const in_t*)d_in[37];
  const in_t* O2   = (const in_t*)d_in[39];
  const in_t* O3   = (const in_t*)d_in[41];
  out_t* out = (out_t*)d_out;

  // ---- workspace ----
  char* wsb = (char*)d_ws;
  size_t off = 0;
  auto alloc = [&](size_t bytes)->void* {
    void* p = wsb + off; off += (bytes + 255) & ~(size_t)255; return p;
  };
  float* pool   = (float*)alloc((size_t)POOL_TOTAL*4);
  sb_t* Wb1T    = (sb_t*)alloc((size_t)1024*12544*2);
  sb_t* Wb2T    = (sb_t*)alloc((size_t)1024*1024*2);
  sb_t* Ws2T    = (sb_t*)alloc((size_t)256*128*2);
  sb_t* Ws3T    = (sb_t*)alloc((size_t)1024*256*2);
  sb_t* A3T     = (sb_t*)alloc((size_t)1024*1024*2);
  sb_t* O3T     = (sb_t*)alloc((size_t)1024*1024*2);
  sb_t* S3T     = (sb_t*)alloc((size_t)1024*1024*2);
  sb_t* G3T     = (sb_t*)alloc((size_t)1024*1024*2);
  sb_t* s2Tall  = (sb_t*)alloc((size_t)4096*1024*2);  // [A2|O2|S2|G2] rows
  sb_t* O1T     = (sb_t*)alloc((size_t)1024*1024*2);
  sb_t* S1T     = (sb_t*)alloc((size_t)1024*1024*2);
  sb_t* A1T     = (sb_t*)alloc((size_t)1024*2048*2);
  sb_t* boxb    = (sb_t*)alloc((size_t)NB*12544*2);
  float* encP   = (float*)alloc((size_t)7*NB*EDIM*4);  // split-K partials (11 MB)
  sb_t* encMidb = (sb_t*)alloc((size_t)NB*EDIM*2);
  float* oB     = (float*)alloc((size_t)NB*EDIM*4);
  sb_t* oBb     = (sb_t*)alloc((size_t)NB*EDIM*2);
  float* hB     = (float*)alloc((size_t)NH*EDIM*4);
  sb_t* hBb     = (sb_t*)alloc((size_t)128*EDIM*2);
  sb_t* sp1b    = (sb_t*)alloc((size_t)PAIRS*128*2);
  sb_t* sp2b    = (sb_t*)alloc((size_t)PAIRS*256*2);
  sb_t* spFb    = (sb_t*)alloc((size_t)PAIRS*EDIM*2); // aliased as mbuf later
  sb_t* mbuf    = spFb;
  sb_t* s4      = (sb_t*)alloc((size_t)PAIRS*4096*2); // [sA|sO|sS|sG]
  float* ahA    = (float*)alloc((size_t)128*EDIM*4);
  float* aoA    = (float*)alloc((size_t)NB*EDIM*4);
  float* aoO    = (float*)alloc((size_t)NB*EDIM*4);
  float* ahS    = (float*)alloc((size_t)128*EDIM*4);
  float* aGv    = (float*)alloc((size_t)EDIM*4);
  float* adj    = (float*)alloc((size_t)PAIRS*4);
  float* wh     = (float*)alloc((size_t)PAIRS*4);
  float* wo     = (float*)alloc((size_t)PAIRS*4);
  sb_t* mwH     = (sb_t*)alloc((size_t)128*EDIM*2);
  sb_t* mwO     = (sb_t*)alloc((size_t)NB*EDIM*2);
  float* hmsg   = (float*)alloc((size_t)128*EDIM*4);
  float* omsg   = (float*)alloc((size_t)NB*EDIM*4);

  // ---- prep ----
  Prep17 pp;
  const int prepIdx[17] = {4,6,8,10,12,20,22,26,28,32,34,38,40,24,30,36,42};
  for (int i=0;i<17;++i) pp.p[i] = (const in_t*)d_in[prepIdx[i]];
  hipLaunchKernelGGL(prep_kernel, dim3(17), dim3(256), 0, stream, pp, pool);
  hipLaunchKernelGGL(gfeat_kernel, dim3(256), dim3(64), 0, stream, f3, pool + POOL_GFEAT);

  hipLaunchKernelGGL(tcvt_kernel, dim3(196,16), dim3(256), 0, stream, Wb1, Wb1T, 12544, 1024);
  hipLaunchKernelGGL(tcvt_kernel, dim3(16,16),  dim3(256), 0, stream, Wb2, Wb2T, 1024, 1024);
  hipLaunchKernelGGL(tcvt_kernel, dim3(2,4),    dim3(256), 0, stream, Ws2, Ws2T, 128, 256);
  hipLaunchKernelGGL(tcvt_kernel, dim3(4,16),   dim3(256), 0, stream, Ws3, Ws3T, 256, 1024);
  hipLaunchKernelGGL(tcvt_kernel, dim3(16,16),  dim3(256), 0, stream, A3, A3T, 1024, 1024);
  hipLaunchKernelGGL(tcvt_kernel, dim3(16,16),  dim3(256), 0, stream, O3, O3T, 1024, 1024);
  hipLaunchKernelGGL(tcvt_kernel, dim3(16,16),  dim3(256), 0, stream, S3, S3T, 1024, 1024);
  hipLaunchKernelGGL(tcvt_kernel, dim3(16,16),  dim3(256), 0, stream, G3, G3T, 1024, 1024);

  hipLaunchKernelGGL(pack_kt_kernel, dim3(16,16), dim3(256), 0, stream, A2, s2Tall,            1024);
  hipLaunchKernelGGL(pack_kt_kernel, dim3(16,16), dim3(256), 0, stream, O2, s2Tall+1024*1024,  1024);
  hipLaunchKernelGGL(pack_kt_kernel, dim3(16,16), dim3(256), 0, stream, S2, s2Tall+2048*1024,  1024);
  hipLaunchKernelGGL(pack_kt_kernel, dim3(16,16), dim3(256), 0, stream, G2, s2Tall+3072*1024,  1024);
  hipLaunchKernelGGL(pack_kt_kernel, dim3(16,16), dim3(256), 0, stream, O1, O1T, 1024);
  hipLaunchKernelGGL(pack_kt_kernel, dim3(16,16), dim3(256), 0, stream, S1, S1T, 1024);
  hipLaunchKernelGGL(pack_kt_kernel, dim3(32,16), dim3(256), 0, stream, A1, A1T, 2048);

  hipLaunchKernelGGL(cvt_kernel, dim3((NB*12544)/256), dim3(256), 0, stream, box, boxb, NB*12544);

  // ---- enc: split-K box GEMM (KS=1792, z=7) + combine, then @Wb2 (split-K) ----
  launch_mfma<2,0,float>(stream, NB, EDIM, 1792, 12544, 12544, 7,
      boxb, Wb1T, nullptr, encP, EDIM, 0, (long long)NB*EDIM, nullptr, nullptr, nullptr);
  hipLaunchKernelGGL((combineN_kernel<sb_t>), dim3(NB*EDIM/256), dim3(256), 0, stream,
                     encP, (long long)NB*EDIM, 7, pool+POOL_BB1, EDIM, 1, encMidb);
  launch_skinny(stream, NB, EDIM, EDIM, EDIM, EDIM, 4,
      encMidb, Wb2T, pool+POOL_BB2, oB, 1, encP);
  hipLaunchKernelGGL(encpost_kernel, dim3(NB,4), dim3(256), 0, stream, oB, oBb, hB, hBb);

  // ---- spatial MLP ----
  {
    dim3 g((PAIRS+63)/64, 2, 1);
    hipLaunchKernelGGL((gemm_valu<sb_t>), g, dim3(256), 0, stream,
        PAIRS, 128, SPA, spat, SPA, Ws1, 128, 0, pool+POOL_BS1, sp1b, 128, 1);
  }
  launch_mfma<0,1,sb_t>(stream, PAIRS, 256, 128, 128, 128, 1,
      sp1b, Ws2T, pool+POOL_BS2, sp2b, 256, 0, 0, nullptr, nullptr, nullptr);
  launch_mfma256<0,1,sb_t>(stream, PAIRS, EDIM, 256, 256, 256,
      sp2b, Ws3T, pool+POOL_BS3, spFb, EDIM, 0, nullptr, nullptr, nullptr);

  // ---- fused s-precompute: s4 = spF @ [A2|O2|S2|G2] + b2  (N=4096) ----
  launch_mfma256<0,0,sb_t>(stream, PAIRS, 4096, EDIM, EDIM, EDIM,
      spFb, s2Tall, pool+POOL_B2ALL, s4, 4096, 0, nullptr, nullptr, nullptr);

  // ---- aG = gfeat @ G1 + Gb1 (single row) ----
  {
    dim3 g(1, 1, 16);
    hipLaunchKernelGGL((gemm_valu<float>), g, dim3(256), 0, stream,
        1, 64, 256, pool+POOL_GFEAT, 256, G1, 64, 16384, pool+POOL_GB1, aGv, EDIM, 0);
  }

  // ---- 2 message-passing iterations ----
  for (int it=0; it<2; ++it) {
    // A-path -> adj
    launch_skinny(stream, 128, EDIM, EDIM, EDIM, 2048, 8,
        hBb, A1T, pool+POOL_AB1, ahA, 0, encP);
    launch_skinny(stream, NB, EDIM, EDIM, EDIM, 2048, 4,
        oBb, A1T+1024, nullptr, aoA, 0, encP);
    hipLaunchKernelGGL(mmake_kernel, dim3(PAIRS), dim3(256), 0, stream,
                       ahA, 1, 1024, aoA, 1, s4, 4096, 0, mbuf);
    (void)hipMemsetAsync(adj, 0, (size_t)PAIRS*4, stream);
    launch_mfma256<1,0,float>(stream, PAIRS, EDIM, EDIM, EDIM, EDIM,
        mbuf, A3T, nullptr, (float*)nullptr, 0, 0, Wadj, pool+POOL_AB3S, adj);
    hipLaunchKernelGGL(smax_h_kernel, dim3(NH), dim3(512), 0, stream, adj, wh);
    hipLaunchKernelGGL(smax_o_kernel, dim3(NB), dim3(64), 0, stream, adj, wo);

    // O-path -> h update
    launch_skinny(stream, NB, EDIM, EDIM, EDIM, 1024, 4,
        oBb, O1T, pool+POOL_OB1, aoO, 0, encP);
    hipLaunchKernelGGL(wredH_kernel, dim3(NH,8), dim3(128), 0, stream,
                       wh, aoO, s4, 1024, mwH);
    launch_skinny(stream, 128, EDIM, EDIM, EDIM, 1024, 8,
        mwH, O3T, nullptr, hmsg, 0, encP);
    hipLaunchKernelGGL(ln_update_kernel, dim3(NH), dim3(1024), 0, stream,
                       hmsg, pool+POOL_OB3S, gh, bh, hB, hBb);

    // S-path -> o update (uses updated h)
    launch_skinny(stream, 128, EDIM, EDIM, EDIM, 1024, 8,
        hBb, S1T, pool+POOL_SB1, ahS, 0, encP);
    hipLaunchKernelGGL(wredO_kernel, dim3(NB,8), dim3(128), 0, stream,
                       wo, ahS, s4, 2048, mwO);
    launch_skinny(stream, NB, EDIM, EDIM, EDIM, 1024, 4,
        mwO, S3T, nullptr, omsg, 0, encP);
    hipLaunchKernelGGL(ln_update_kernel, dim3(NB), dim3(1024), 0, stream,
                       omsg, pool+POOL_SB3S, go, bo, oB, oBb);
  }

  // ---- final heads ----
  launch_skinny(stream, 128, EDIM, EDIM, EDIM, 2048, 8,
      hBb, A1T, pool+POOL_AB1, ahA, 0, encP);
  launch_skinny(stream, NB, EDIM, EDIM, EDIM, 2048, 4,
      oBb, A1T+1024, nullptr, aoA, 0, encP);
  hipLaunchKernelGGL(mmake_kernel, dim3(PAIRS), dim3(256), 0, stream,
                     ahA, 1, 1024, aoA, 1, s4, 4096, 0, mbuf);
  launch_mfma256<0,1,out_t>(stream, PAIRS, EDIM, EDIM, EDIM, EDIM,
      mbuf, A3T, pool+POOL_AB3S, out, 2048, 0, nullptr, nullptr, nullptr);

  hipLaunchKernelGGL(mmake_kernel, dim3(PAIRS), dim3(256), 0, stream,
                     aGv, 1, 0, nullptr, 0, s4, 4096, 3072, mbuf);
  launch_mfma256<0,1,out_t>(stream, PAIRS, EDIM, EDIM, EDIM, EDIM,
      mbuf, G3T, pool+POOL_GB3S, out, 2048, 1024, nullptr, nullptr, nullptr);
}